// Round 2
// baseline (19586.388 us; speedup 1.0000x reference)
//
#include <hip/hip_runtime.h>

#define BB 16
#define NN 4096
#define SS 1024
#define KK 32
#define MPTS (BB*SS*KK)      // 524288
#define EPSF 1e-5f

// workspace layout (float offsets)
#define OFF_QP    0                       // B*S*4  (qx,qy,qz,q2)
#define OFF_P4    (OFF_QP + BB*SS*4)      // B*N*4  (x,y,z,x2)
#define OFF_ST    (OFF_P4 + BB*NN*4)      // 512 floats, zeroed each call
#define OFF_MOM   (OFF_ST)                // 27
#define OFF_S1SUM (OFF_ST+32)             // 64
#define OFF_S1SQ  (OFF_ST+96)             // 64
#define OFF_S2SUM (OFF_ST+160)            // 128
#define OFF_S2SQ  (OFF_ST+288)            // 128
#define OFF_SC0   (OFF_ST+512)
#define OFF_SH0   (OFF_SC0+64)
#define OFF_SC1   (OFF_SH0+64)
#define OFF_SH1   (OFF_SC1+64)
#define OFF_XG    (OFF_SH1+64)            // 6*MPTS channel-major
#define OFF_MAXB  (OFF_XG + 6*MPTS)       // B*S*128
#define OFF_MINB  (OFF_MAXB + BB*SS*128)  // B*S*128

__global__ __launch_bounds__(256) void prep_kernel(
    const float* __restrict__ xyz, const int* __restrict__ fps,
    float* __restrict__ out, float* __restrict__ ws)
{
  const int g = blockIdx.x*256 + threadIdx.x;
  if (g < BB*NN){
    const float* p = xyz + (size_t)g*3;
    float x=p[0], y=p[1], z=p[2];
    float x2 = __fadd_rn(__fadd_rn(__fmul_rn(x,x),__fmul_rn(y,y)),__fmul_rn(z,z));
    *reinterpret_cast<float4*>(ws + OFF_P4 + (size_t)g*4) = make_float4(x,y,z,x2);
  } else {
    int j = g - BB*NN;
    if (j < BB*SS){
      int b = j >> 10;
      int idx = fps[j];
      const float* p = xyz + ((size_t)b*NN + idx)*3;
      float x=p[0], y=p[1], z=p[2];
      out[(size_t)j*3+0]=x; out[(size_t)j*3+1]=y; out[(size_t)j*3+2]=z;
      float q2 = __fadd_rn(__fadd_rn(__fmul_rn(x,x),__fmul_rn(y,y)),__fmul_rn(z,z));
      *reinterpret_cast<float4*>(ws + OFF_QP + (size_t)j*4) = make_float4(x,y,z,q2);
    }
  }
}

// one block per query: exact 32-NN via radix-select on orderable float bits,
// writes grouped input (channel-major) and accumulates layer-0 input moments.
__global__ __launch_bounds__(256) void knn_group_kernel(
    const float* __restrict__ pts, float* __restrict__ ws)
{
  __shared__ unsigned keys[NN];
  __shared__ unsigned hist[256];
  __shared__ unsigned wsum[4];
  __shared__ unsigned sh_bin, sh_knew;
  __shared__ int sh_nlt, sh_neq;
  __shared__ int sel[KK];
  __shared__ int eqlist[256];

  const int bid = blockIdx.x;
  const int b = bid >> 10;
  const int tid = threadIdx.x;
  const int lane = tid & 63;
  const int wv = tid >> 6;

  const float4 q = *reinterpret_cast<const float4*>(ws + OFF_QP + (size_t)bid*4);
  const float qx=q.x, qy=q.y, qz=q.z, q2=q.w;
  const float4* pb = reinterpret_cast<const float4*>(ws + OFF_P4) + (size_t)b*NN;

  #pragma unroll
  for (int j=0;j<16;j++){
    int n = tid + j*256;
    float4 P = pb[n];
    float dot = __fadd_rn(__fadd_rn(__fmul_rn(qx,P.x),__fmul_rn(qy,P.y)),__fmul_rn(qz,P.z));
    float d = __fsub_rn(__fadd_rn(q2, P.w), __fmul_rn(2.0f,dot));
    unsigned u = __float_as_uint(d);
    keys[n] = u ^ (unsigned)(((int)u>>31) | (int)0x80000000);
  }
  __syncthreads();

  unsigned prefix = 0;
  int kk = KK;
  for (int pass=3; pass>=0; --pass){
    const int shift = pass*8;
    const unsigned maskhi = (pass==3) ? 0u : (0xFFFFFFFFu << (shift+8));
    hist[tid] = 0;
    __syncthreads();
    #pragma unroll
    for (int j=0;j<16;j++){
      unsigned key = keys[tid + j*256];
      if ((key & maskhi) == prefix) atomicAdd(&hist[(key>>shift)&0xFFu], 1u);
    }
    __syncthreads();
    unsigned orig = hist[tid];
    unsigned v = orig;
    #pragma unroll
    for (int off=1; off<64; off<<=1){
      unsigned u = __shfl_up(v, (unsigned)off, 64);
      if (lane >= off) v += u;
    }
    if (lane==63) wsum[wv] = v;
    __syncthreads();
    unsigned add = 0;
    #pragma unroll
    for (int k=0;k<3;k++) if (wv > k) add += wsum[k];
    unsigned cumt = v + add;
    unsigned lower = cumt - orig;
    if (cumt >= (unsigned)kk && lower < (unsigned)kk){
      sh_bin = (unsigned)tid; sh_knew = (unsigned)kk - lower;
    }
    __syncthreads();
    prefix |= (sh_bin << shift);
    kk = (int)sh_knew;
  }
  const unsigned v32 = prefix;

  if (tid==0){ sh_nlt = 0; sh_neq = 0; }
  __syncthreads();
  #pragma unroll
  for (int j=0;j<16;j++){
    int n = tid + j*256;
    unsigned key = keys[n];
    if (key < v32){ int p = atomicAdd(&sh_nlt,1); sel[p] = n; }
    else if (key == v32){ int p = atomicAdd(&sh_neq,1); if (p < 256) eqlist[p] = n; }
  }
  __syncthreads();
  if (tid==0){
    int nlt = sh_nlt;
    int need = KK - nlt;
    int neq = sh_neq;
    if (neq <= 256){
      for (int a=0;a<need;a++){          // lowest-index ties first (top_k semantics)
        int mi = a;
        for (int c=a+1;c<neq;c++) if (eqlist[c] < eqlist[mi]) mi = c;
        int t = eqlist[a]; eqlist[a]=eqlist[mi]; eqlist[mi]=t;
        sel[nlt+a] = eqlist[a];
      }
    } else {
      int got = 0;
      for (int n=0;n<NN && got<need;n++) if (keys[n]==v32){ sel[nlt+got]=n; ++got; }
    }
  }
  __syncthreads();

  if (tid < KK){
    int n = sel[tid];
    float4 P = pb[n];
    float v6[6];
    v6[0] = P.x-qx; v6[1] = P.y-qy; v6[2] = P.z-qz;
    const float* pt = pts + ((size_t)b*NN + n)*3;
    v6[3] = pt[0]; v6[4] = pt[1]; v6[5] = pt[2];
    size_t pidx = (size_t)bid*KK + tid;
    float* xg = ws + OFF_XG;
    #pragma unroll
    for (int c=0;c<6;c++) xg[(size_t)c*MPTS + pidx] = v6[c];
    // layer-0 input moments (6 sums + 21 upper-tri products)
    float m[27];
    int mi = 0;
    #pragma unroll
    for (int c=0;c<6;c++) m[mi++] = v6[c];
    #pragma unroll
    for (int c=0;c<6;c++){
      #pragma unroll
      for (int c2=c;c2<6;c2++) m[mi++] = v6[c]*v6[c2];
    }
    #pragma unroll
    for (int off=16; off>=1; off>>=1){
      #pragma unroll
      for (int qq=0;qq<27;qq++) m[qq] += __shfl_xor(m[qq], off, 64);
    }
    if (tid==0){
      float* mom = ws + OFF_MOM;
      #pragma unroll
      for (int qq=0;qq<27;qq++) atomicAdd(&mom[qq], m[qq]);
    }
  }
}

__global__ void finalize0_kernel(const float* __restrict__ w0, const float* __restrict__ b0,
                                 const float* __restrict__ g0, const float* __restrict__ t0,
                                 float* __restrict__ ws)
{
  int o = threadIdx.x; // 64 threads
  const float* mom = ws + OFF_MOM;
  float w[6];
  #pragma unroll
  for (int c=0;c<6;c++) w[c] = w0[o*6+c];
  float bo = b0[o];
  float wS = 0.f;
  #pragma unroll
  for (int c=0;c<6;c++) wS += w[c]*mom[c];
  const float Mf = (float)MPTS;
  float mean = (wS + Mf*bo) / Mf;
  float qsum = 0.f;
  int mi = 6;
  #pragma unroll
  for (int c=0;c<6;c++){
    #pragma unroll
    for (int c2=c;c2<6;c2++){
      float f = (c==c2)?1.f:2.f;
      qsum += f * w[c]*w[c2]*mom[mi];
      mi++;
    }
  }
  float E2  = (qsum + 2.f*bo*wS + Mf*bo*bo) / Mf;
  float var = E2 - mean*mean;
  float sc  = g0[o] / sqrtf(var + EPSF);
  ws[OFF_SC0+o] = sc;
  ws[OFF_SH0+o] = t0[o] - mean*sc;
}

// per thread one point: h0_c on the fly (c-outer), accumulate y1 into acc[64],
// reduce sums/sumsq per channel. No big register-indexed arrays, no spill.
__global__ __launch_bounds__(256,4) void layer1_stats_kernel(
    const float* __restrict__ w0g, const float* __restrict__ b0g,
    const float* __restrict__ w1g, const float* __restrict__ b1g,
    float* __restrict__ ws)
{
  __shared__ float sw0[64*8];    // padded rows: w0[c][0..5] at c*8
  __shared__ float sw1T[4096];   // [c][o]
  __shared__ float sb0[64], ssc0[64], ssh0[64], sb1[64];
  __shared__ float red[128];
  const int tid = threadIdx.x;
  for (int i=tid;i<384;i+=256){ int o=i/6, c=i-o*6; sw0[o*8+c] = w0g[i]; }
  for (int i=tid;i<4096;i+=256){ int o=i>>6, c=i&63; sw1T[c*64+o] = w1g[i]; }
  if (tid<64){ sb0[tid]=b0g[tid]; sb1[tid]=b1g[tid];
               ssc0[tid]=ws[OFF_SC0+tid]; ssh0[tid]=ws[OFF_SH0+tid]; }
  if (tid<128) red[tid]=0.f;
  __syncthreads();

  const size_t p = (size_t)blockIdx.x*256 + tid;
  const float* xg = ws + OFF_XG;
  float x[6];
  #pragma unroll
  for (int c=0;c<6;c++) x[c] = xg[(size_t)c*MPTS + p];

  float acc[64];
  #pragma unroll
  for (int o=0;o<64;o++) acc[o] = sb1[o];

  for (int c=0;c<64;c++){
    const float4 wa = *reinterpret_cast<const float4*>(&sw0[c*8]);
    const float2 wb = *reinterpret_cast<const float2*>(&sw0[c*8+4]);
    float y = sb0[c];
    y = fmaf(wa.x,x[0],y); y = fmaf(wa.y,x[1],y); y = fmaf(wa.z,x[2],y);
    y = fmaf(wa.w,x[3],y); y = fmaf(wb.x,x[4],y); y = fmaf(wb.y,x[5],y);
    const float h = fmaxf(fmaf(ssc0[c], y, ssh0[c]), 0.f);
    const float4* wr = reinterpret_cast<const float4*>(&sw1T[c*64]);
    #pragma unroll
    for (int qq=0;qq<16;qq++){
      float4 wvv = wr[qq];
      acc[qq*4+0] = fmaf(wvv.x,h,acc[qq*4+0]);
      acc[qq*4+1] = fmaf(wvv.y,h,acc[qq*4+1]);
      acc[qq*4+2] = fmaf(wvv.z,h,acc[qq*4+2]);
      acc[qq*4+3] = fmaf(wvv.w,h,acc[qq*4+3]);
    }
  }
  const int lane = tid & 63;
  #pragma unroll
  for (int o=0;o<64;o++){
    float sv = acc[o];
    float sq = acc[o]*acc[o];
    #pragma unroll
    for (int off=32; off>=1; off>>=1){
      sv += __shfl_xor(sv, off, 64);
      sq += __shfl_xor(sq, off, 64);
    }
    if (lane == o){
      atomicAdd(&red[o],    sv);
      atomicAdd(&red[64+o], sq);
    }
  }
  __syncthreads();
  if (tid < 128) atomicAdd(&ws[OFF_S1SUM + tid], red[tid]);
}

__global__ void finalize1_kernel(const float* __restrict__ g1, const float* __restrict__ t1,
                                 float* __restrict__ ws)
{
  int o = threadIdx.x;
  const float Mf = (float)MPTS;
  float mean = ws[OFF_S1SUM+o]/Mf;
  float var  = ws[OFF_S1SQ+o]/Mf - mean*mean;
  float sc = g1[o]/sqrtf(var+EPSF);
  ws[OFF_SC1+o]=sc; ws[OFF_SH1+o]=t1[o]-mean*sc;
}

// full chain per point: h1 via c-outer acc, then y2 in 8 chunks of 16 channels.
__global__ __launch_bounds__(256,3) void layer2_max_kernel(
    const float* __restrict__ w0g, const float* __restrict__ b0g,
    const float* __restrict__ w1g, const float* __restrict__ b1g,
    const float* __restrict__ w2g, const float* __restrict__ b2g,
    float* __restrict__ ws)
{
  __shared__ float sw0[64*8];
  __shared__ float sw1T[4096];   // [c][o] 64x64
  __shared__ float sw2T[8192];   // [c][o] 64x128
  __shared__ float sb0[64], ssc0[64], ssh0[64], sb1[64], ssc1[64], ssh1[64], sb2[128];
  __shared__ float red[256];
  const int tid = threadIdx.x;
  for (int i=tid;i<384;i+=256){ int o=i/6, c=i-o*6; sw0[o*8+c] = w0g[i]; }
  for (int i=tid;i<4096;i+=256){ int o=i>>6, c=i&63; sw1T[c*64+o] = w1g[i]; }
  for (int i=tid;i<8192;i+=256){ int o=i>>6, c=i&63; sw2T[c*128+o] = w2g[i]; }
  if (tid<64){ sb0[tid]=b0g[tid]; sb1[tid]=b1g[tid];
               ssc0[tid]=ws[OFF_SC0+tid]; ssh0[tid]=ws[OFF_SH0+tid];
               ssc1[tid]=ws[OFF_SC1+tid]; ssh1[tid]=ws[OFF_SH1+tid]; }
  if (tid<128) sb2[tid]=b2g[tid];
  red[tid]=0.f;
  __syncthreads();

  const size_t p = (size_t)blockIdx.x*256 + tid;
  const float* xg = ws + OFF_XG;
  float x[6];
  #pragma unroll
  for (int c=0;c<6;c++) x[c] = xg[(size_t)c*MPTS + p];

  float h1[64];
  #pragma unroll
  for (int o=0;o<64;o++) h1[o] = sb1[o];

  for (int c=0;c<64;c++){
    const float4 wa = *reinterpret_cast<const float4*>(&sw0[c*8]);
    const float2 wb = *reinterpret_cast<const float2*>(&sw0[c*8+4]);
    float y = sb0[c];
    y = fmaf(wa.x,x[0],y); y = fmaf(wa.y,x[1],y); y = fmaf(wa.z,x[2],y);
    y = fmaf(wa.w,x[3],y); y = fmaf(wb.x,x[4],y); y = fmaf(wb.y,x[5],y);
    const float h = fmaxf(fmaf(ssc0[c], y, ssh0[c]), 0.f);
    const float4* wr = reinterpret_cast<const float4*>(&sw1T[c*64]);
    #pragma unroll
    for (int qq=0;qq<16;qq++){
      float4 wvv = wr[qq];
      h1[qq*4+0] = fmaf(wvv.x,h,h1[qq*4+0]);
      h1[qq*4+1] = fmaf(wvv.y,h,h1[qq*4+1]);
      h1[qq*4+2] = fmaf(wvv.z,h,h1[qq*4+2]);
      h1[qq*4+3] = fmaf(wvv.w,h,h1[qq*4+3]);
    }
  }
  #pragma unroll
  for (int o=0;o<64;o++) h1[o] = fmaxf(fmaf(ssc1[o], h1[o], ssh1[o]), 0.f);

  const int lane = tid & 63;
  const int l32  = tid & 31;
  const size_t gidx = p >> 5;
  float* maxb = ws + OFF_MAXB;
  float* minb = ws + OFF_MINB;

  for (int oc=0; oc<8; ++oc){
    float a[16];
    #pragma unroll
    for (int j=0;j<16;j++) a[j] = sb2[oc*16+j];
    #pragma unroll
    for (int c=0;c<64;c++){
      const float4* wr = reinterpret_cast<const float4*>(&sw2T[c*128 + oc*16]);
      const float h = h1[c];
      #pragma unroll
      for (int qq=0;qq<4;qq++){
        float4 wvv = wr[qq];
        a[qq*4+0] = fmaf(wvv.x,h,a[qq*4+0]);
        a[qq*4+1] = fmaf(wvv.y,h,a[qq*4+1]);
        a[qq*4+2] = fmaf(wvv.z,h,a[qq*4+2]);
        a[qq*4+3] = fmaf(wvv.w,h,a[qq*4+3]);
      }
    }
    #pragma unroll
    for (int j=0;j<16;j++){
      const int o = oc*16 + j;       // oc runtime, but only used for LDS/global addrs
      float sv = a[j], sq = a[j]*a[j];
      #pragma unroll
      for (int off=32; off>=1; off>>=1){
        sv += __shfl_xor(sv,off,64);
        sq += __shfl_xor(sq,off,64);
      }
      if (lane == (o & 63)){
        atomicAdd(&red[o],     sv);
        atomicAdd(&red[128+o], sq);
      }
      float mx = a[j], mn = a[j];
      #pragma unroll
      for (int off=16; off>=1; off>>=1){
        mx = fmaxf(mx, __shfl_xor(mx,off,64));
        mn = fminf(mn, __shfl_xor(mn,off,64));
      }
      if (l32 == (o & 31)){
        maxb[gidx*128 + o] = mx;
        minb[gidx*128 + o] = mn;
      }
    }
  }
  __syncthreads();
  atomicAdd(&ws[OFF_S2SUM + tid], red[tid]);
}

__global__ __launch_bounds__(256) void final_out_kernel(
    const float* __restrict__ g2, const float* __restrict__ t2,
    const float* __restrict__ ws, float* __restrict__ out)
{
  const int g = blockIdx.x*256 + threadIdx.x; // B*S*128 threads
  const int o = g & 127;
  const float Mf = (float)MPTS;
  float mean = ws[OFF_S2SUM+o] / Mf;
  float var  = ws[OFF_S2SQ+o] / Mf - mean*mean;
  float sc = g2[o] / sqrtf(var + EPSF);
  float sh = t2[o] - mean*sc;
  // relu(sc*y+sh) is monotone in y: use group max if sc>0 else group min
  float v = (sc > 0.f) ? ws[OFF_MAXB+g] : ws[OFF_MINB+g];
  out[BB*SS*3 + g] = fmaxf(fmaf(sc, v, sh), 0.f);
}

extern "C" void kernel_launch(void* const* d_in, const int* in_sizes, int n_in,
                              void* d_out, int out_size, void* d_ws, size_t ws_size,
                              hipStream_t stream)
{
  const float* xyz = (const float*)d_in[0];
  const float* pts = (const float*)d_in[1];
  const int*   fps = (const int*)d_in[2];
  const float* w0  = (const float*)d_in[3];
  const float* b0  = (const float*)d_in[4];
  const float* g0  = (const float*)d_in[5];
  const float* t0  = (const float*)d_in[6];
  const float* w1  = (const float*)d_in[7];
  const float* b1  = (const float*)d_in[8];
  const float* g1  = (const float*)d_in[9];
  const float* t1  = (const float*)d_in[10];
  const float* w2  = (const float*)d_in[11];
  const float* b2  = (const float*)d_in[12];
  const float* g2  = (const float*)d_in[13];
  const float* t2  = (const float*)d_in[14];
  float* out = (float*)d_out;
  float* ws  = (float*)d_ws;

  hipMemsetAsync((void*)(ws + OFF_ST), 0, 512*sizeof(float), stream);
  prep_kernel<<<320,256,0,stream>>>(xyz, fps, out, ws);
  knn_group_kernel<<<BB*SS,256,0,stream>>>(pts, ws);
  finalize0_kernel<<<1,64,0,stream>>>(w0,b0,g0,t0,ws);
  layer1_stats_kernel<<<MPTS/256,256,0,stream>>>(w0,b0,w1,b1,ws);
  finalize1_kernel<<<1,64,0,stream>>>(g1,t1,ws);
  layer2_max_kernel<<<MPTS/256,256,0,stream>>>(w0,b0,w1,b1,w2,b2,ws);
  final_out_kernel<<<(BB*SS*128)/256,256,0,stream>>>(g2,t2,ws,out);
}

// Round 3
// 18296.524 us; speedup vs baseline: 1.0705x; 1.0705x over previous
//
#include <hip/hip_runtime.h>

#define BB 16
#define NN 4096
#define SS 1024
#define KK 32
#define MPTS (BB*SS*KK)      // 524288
#define EPSF 1e-5f

// workspace layout (float offsets)
#define OFF_QP    0                       // B*S*4  (qx,qy,qz,q2)
#define OFF_P4    (OFF_QP + BB*SS*4)      // B*N*4  (x,y,z,x2)
#define OFF_ST    (OFF_P4 + BB*NN*4)      // 512 floats, zeroed each call
#define OFF_MOM   (OFF_ST)                // 27
#define OFF_S1SUM (OFF_ST+32)             // 64
#define OFF_S1SQ  (OFF_ST+96)             // 64
#define OFF_S2SUM (OFF_ST+160)            // 128
#define OFF_S2SQ  (OFF_ST+288)            // 128
#define OFF_SC0   (OFF_ST+512)
#define OFF_SH0   (OFF_SC0+64)
#define OFF_SC1   (OFF_SH0+64)
#define OFF_SH1   (OFF_SC1+64)
#define OFF_XG    (OFF_SH1+64)            // 6*MPTS channel-major
#define OFF_MAXB  (OFF_XG + 6*MPTS)       // B*S*128
#define OFF_MINB  (OFF_MAXB + BB*SS*128)  // B*S*128

__global__ __launch_bounds__(256) void prep_kernel(
    const float* __restrict__ xyz, const int* __restrict__ fps,
    float* __restrict__ out, float* __restrict__ ws)
{
  const int g = blockIdx.x*256 + threadIdx.x;
  if (g < BB*NN){
    const float* p = xyz + (size_t)g*3;
    float x=p[0], y=p[1], z=p[2];
    float x2 = __fadd_rn(__fadd_rn(__fmul_rn(x,x),__fmul_rn(y,y)),__fmul_rn(z,z));
    *reinterpret_cast<float4*>(ws + OFF_P4 + (size_t)g*4) = make_float4(x,y,z,x2);
  } else {
    int j = g - BB*NN;
    if (j < BB*SS){
      int b = j >> 10;
      int idx = fps[j];
      const float* p = xyz + ((size_t)b*NN + idx)*3;
      float x=p[0], y=p[1], z=p[2];
      out[(size_t)j*3+0]=x; out[(size_t)j*3+1]=y; out[(size_t)j*3+2]=z;
      float q2 = __fadd_rn(__fadd_rn(__fmul_rn(x,x),__fmul_rn(y,y)),__fmul_rn(z,z));
      *reinterpret_cast<float4*>(ws + OFF_QP + (size_t)j*4) = make_float4(x,y,z,q2);
    }
  }
}

// one block per query: exact 32-NN via radix-select on orderable float bits.
// Histogram uses ballot-leader counting (no same-address LDS atomic storms).
__global__ __launch_bounds__(256) void knn_group_kernel(
    const float* __restrict__ pts, float* __restrict__ ws)
{
  __shared__ unsigned keys[NN];
  __shared__ unsigned hist[256];
  __shared__ unsigned wsum[4];
  __shared__ unsigned sh_bin, sh_knew;
  __shared__ int sh_nlt, sh_neq;
  __shared__ int sel[KK];
  __shared__ int eqlist[256];

  const int bid = blockIdx.x;
  const int b = bid >> 10;
  const int tid = threadIdx.x;
  const int lane = tid & 63;
  const int wv = tid >> 6;

  const float4 q = *reinterpret_cast<const float4*>(ws + OFF_QP + (size_t)bid*4);
  const float qx=q.x, qy=q.y, qz=q.z, q2=q.w;
  const float4* pb = reinterpret_cast<const float4*>(ws + OFF_P4) + (size_t)b*NN;

  #pragma unroll
  for (int j=0;j<16;j++){
    int n = tid + j*256;
    float4 P = pb[n];
    float dot = __fadd_rn(__fadd_rn(__fmul_rn(qx,P.x),__fmul_rn(qy,P.y)),__fmul_rn(qz,P.z));
    float d = __fsub_rn(__fadd_rn(q2, P.w), __fmul_rn(2.0f,dot));
    unsigned u = __float_as_uint(d);
    keys[n] = u ^ (unsigned)(((int)u>>31) | (int)0x80000000);
  }
  __syncthreads();

  const unsigned long long mlt = (lane==0) ? 0ull : (~0ull >> (64-lane));
  unsigned prefix = 0;
  int kk = KK;
  for (int pass=3; pass>=0; --pass){
    const int shift = pass*8;
    const unsigned maskhi = (pass==3) ? 0u : (0xFFFFFFFFu << (shift+8));
    hist[tid] = 0;
    __syncthreads();
    #pragma unroll
    for (int j=0;j<16;j++){
      unsigned key = keys[tid + j*256];
      bool act = ((key & maskhi) == prefix);
      if (__any((int)act)){
        unsigned bin = (key>>shift)&0xFFu;
        unsigned long long m = __ballot((int)act);
        #pragma unroll
        for (int bit=0;bit<8;bit++){
          unsigned long long bb = __ballot((int)(act && ((bin>>bit)&1u)));
          m &= ((bin>>bit)&1u) ? bb : ~bb;
        }
        if (act && (m & mlt) == 0ull)
          atomicAdd(&hist[bin], (unsigned)__popcll(m));
      }
    }
    __syncthreads();
    unsigned orig = hist[tid];
    unsigned v = orig;
    #pragma unroll
    for (int off=1; off<64; off<<=1){
      unsigned u = __shfl_up(v, (unsigned)off, 64);
      if (lane >= off) v += u;
    }
    if (lane==63) wsum[wv] = v;
    __syncthreads();
    unsigned add = 0;
    #pragma unroll
    for (int k=0;k<3;k++) if (wv > k) add += wsum[k];
    unsigned cumt = v + add;
    unsigned lower = cumt - orig;
    if (cumt >= (unsigned)kk && lower < (unsigned)kk){
      sh_bin = (unsigned)tid; sh_knew = (unsigned)kk - lower;
    }
    __syncthreads();
    prefix |= (sh_bin << shift);
    kk = (int)sh_knew;
  }
  const unsigned v32 = prefix;

  if (tid==0){ sh_nlt = 0; sh_neq = 0; }
  __syncthreads();
  #pragma unroll
  for (int j=0;j<16;j++){
    int n = tid + j*256;
    unsigned key = keys[n];
    if (key < v32){ int p = atomicAdd(&sh_nlt,1); sel[p] = n; }
    else if (key == v32){ int p = atomicAdd(&sh_neq,1); if (p < 256) eqlist[p] = n; }
  }
  __syncthreads();
  if (tid==0){
    int nlt = sh_nlt;
    int need = KK - nlt;
    int neq = sh_neq;
    if (neq <= 256){
      for (int a=0;a<need;a++){          // lowest-index ties first (top_k semantics)
        int mi = a;
        for (int c=a+1;c<neq;c++) if (eqlist[c] < eqlist[mi]) mi = c;
        int t = eqlist[a]; eqlist[a]=eqlist[mi]; eqlist[mi]=t;
        sel[nlt+a] = eqlist[a];
      }
    } else {
      int got = 0;
      for (int n=0;n<NN && got<need;n++) if (keys[n]==v32){ sel[nlt+got]=n; ++got; }
    }
  }
  __syncthreads();

  if (tid < KK){
    int n = sel[tid];
    float4 P = pb[n];
    float v6[6];
    v6[0] = P.x-qx; v6[1] = P.y-qy; v6[2] = P.z-qz;
    const float* pt = pts + ((size_t)b*NN + n)*3;
    v6[3] = pt[0]; v6[4] = pt[1]; v6[5] = pt[2];
    size_t pidx = (size_t)bid*KK + tid;
    float* xg = ws + OFF_XG;
    #pragma unroll
    for (int c=0;c<6;c++) xg[(size_t)c*MPTS + pidx] = v6[c];
    // layer-0 input moments (6 sums + 21 upper-tri products)
    float m[27];
    int mi = 0;
    #pragma unroll
    for (int c=0;c<6;c++) m[mi++] = v6[c];
    #pragma unroll
    for (int c=0;c<6;c++){
      #pragma unroll
      for (int c2=c;c2<6;c2++) m[mi++] = v6[c]*v6[c2];
    }
    #pragma unroll
    for (int off=16; off>=1; off>>=1){
      #pragma unroll
      for (int qq=0;qq<27;qq++) m[qq] += __shfl_xor(m[qq], off, 64);
    }
    if (tid==0){
      float* mom = ws + OFF_MOM;
      #pragma unroll
      for (int qq=0;qq<27;qq++) atomicAdd(&mom[qq], m[qq]);
    }
  }
}

__global__ void finalize0_kernel(const float* __restrict__ w0, const float* __restrict__ b0,
                                 const float* __restrict__ g0, const float* __restrict__ t0,
                                 float* __restrict__ ws)
{
  int o = threadIdx.x; // 64 threads
  const float* mom = ws + OFF_MOM;
  float w[6];
  #pragma unroll
  for (int c=0;c<6;c++) w[c] = w0[o*6+c];
  float bo = b0[o];
  float wS = 0.f;
  #pragma unroll
  for (int c=0;c<6;c++) wS += w[c]*mom[c];
  const float Mf = (float)MPTS;
  float mean = (wS + Mf*bo) / Mf;
  float qsum = 0.f;
  int mi = 6;
  #pragma unroll
  for (int c=0;c<6;c++){
    #pragma unroll
    for (int c2=c;c2<6;c2++){
      float f = (c==c2)?1.f:2.f;
      qsum += f * w[c]*w[c2]*mom[mi];
      mi++;
    }
  }
  float E2  = (qsum + 2.f*bo*wS + Mf*bo*bo) / Mf;
  float var = E2 - mean*mean;
  float sc  = g0[o] / sqrtf(var + EPSF);
  ws[OFF_SC0+o] = sc;
  ws[OFF_SH0+o] = t0[o] - mean*sc;
}

// per thread one point: h0_c on the fly (c-outer), accumulate y1 into acc[64].
__global__ __launch_bounds__(256,2) void layer1_stats_kernel(
    const float* __restrict__ w0g, const float* __restrict__ b0g,
    const float* __restrict__ w1g, const float* __restrict__ b1g,
    float* __restrict__ ws)
{
  __shared__ float sw0[64*8];    // padded rows: w0[c][0..5] at c*8
  __shared__ float sw1T[4096];   // [c][o]
  __shared__ float sb0[64], ssc0[64], ssh0[64], sb1[64];
  __shared__ float red[128];
  const int tid = threadIdx.x;
  for (int i=tid;i<384;i+=256){ int o=i/6, c=i-o*6; sw0[o*8+c] = w0g[i]; }
  for (int i=tid;i<4096;i+=256){ int o=i>>6, c=i&63; sw1T[c*64+o] = w1g[i]; }
  if (tid<64){ sb0[tid]=b0g[tid]; sb1[tid]=b1g[tid];
               ssc0[tid]=ws[OFF_SC0+tid]; ssh0[tid]=ws[OFF_SH0+tid]; }
  if (tid<128) red[tid]=0.f;
  __syncthreads();

  const size_t p = (size_t)blockIdx.x*256 + tid;
  const float* xg = ws + OFF_XG;
  float x[6];
  #pragma unroll
  for (int c=0;c<6;c++) x[c] = xg[(size_t)c*MPTS + p];

  float acc[64];
  #pragma unroll
  for (int o=0;o<64;o++) acc[o] = sb1[o];

  for (int c=0;c<64;c++){
    const float4 wa = *reinterpret_cast<const float4*>(&sw0[c*8]);
    const float2 wb = *reinterpret_cast<const float2*>(&sw0[c*8+4]);
    float y = sb0[c];
    y = fmaf(wa.x,x[0],y); y = fmaf(wa.y,x[1],y); y = fmaf(wa.z,x[2],y);
    y = fmaf(wa.w,x[3],y); y = fmaf(wb.x,x[4],y); y = fmaf(wb.y,x[5],y);
    const float h = fmaxf(fmaf(ssc0[c], y, ssh0[c]), 0.f);
    const float4* wr = reinterpret_cast<const float4*>(&sw1T[c*64]);
    #pragma unroll
    for (int qq=0;qq<16;qq++){
      float4 wvv = wr[qq];
      acc[qq*4+0] = fmaf(wvv.x,h,acc[qq*4+0]);
      acc[qq*4+1] = fmaf(wvv.y,h,acc[qq*4+1]);
      acc[qq*4+2] = fmaf(wvv.z,h,acc[qq*4+2]);
      acc[qq*4+3] = fmaf(wvv.w,h,acc[qq*4+3]);
    }
  }
  const int lane = tid & 63;
  #pragma unroll
  for (int o=0;o<64;o++){
    float sv = acc[o];
    float sq = acc[o]*acc[o];
    #pragma unroll
    for (int off=32; off>=1; off>>=1){
      sv += __shfl_xor(sv, off, 64);
      sq += __shfl_xor(sq, off, 64);
    }
    if (lane == o){
      atomicAdd(&red[o],    sv);
      atomicAdd(&red[64+o], sq);
    }
  }
  __syncthreads();
  if (tid < 128) atomicAdd(&ws[OFF_S1SUM + tid], red[tid]);
}

__global__ void finalize1_kernel(const float* __restrict__ g1, const float* __restrict__ t1,
                                 float* __restrict__ ws)
{
  int o = threadIdx.x;
  const float Mf = (float)MPTS;
  float mean = ws[OFF_S1SUM+o]/Mf;
  float var  = ws[OFF_S1SQ+o]/Mf - mean*mean;
  float sc = g1[o]/sqrtf(var+EPSF);
  ws[OFF_SC1+o]=sc; ws[OFF_SH1+o]=t1[o]-mean*sc;
}

// full chain per point: h1 via c-outer acc, then y2 in 8 chunks of 16 channels.
__global__ __launch_bounds__(256,2) void layer2_max_kernel(
    const float* __restrict__ w0g, const float* __restrict__ b0g,
    const float* __restrict__ w1g, const float* __restrict__ b1g,
    const float* __restrict__ w2g, const float* __restrict__ b2g,
    float* __restrict__ ws)
{
  __shared__ float sw0[64*8];
  __shared__ float sw1T[4096];   // [c][o] 64x64
  __shared__ float sw2T[8192];   // [c][o] 64x128
  __shared__ float sb0[64], ssc0[64], ssh0[64], sb1[64], ssc1[64], ssh1[64], sb2[128];
  __shared__ float red[256];
  const int tid = threadIdx.x;
  for (int i=tid;i<384;i+=256){ int o=i/6, c=i-o*6; sw0[o*8+c] = w0g[i]; }
  for (int i=tid;i<4096;i+=256){ int o=i>>6, c=i&63; sw1T[c*64+o] = w1g[i]; }
  for (int i=tid;i<8192;i+=256){ int o=i>>6, c=i&63; sw2T[c*128+o] = w2g[i]; }
  if (tid<64){ sb0[tid]=b0g[tid]; sb1[tid]=b1g[tid];
               ssc0[tid]=ws[OFF_SC0+tid]; ssh0[tid]=ws[OFF_SH0+tid];
               ssc1[tid]=ws[OFF_SC1+tid]; ssh1[tid]=ws[OFF_SH1+tid]; }
  if (tid<128) sb2[tid]=b2g[tid];
  red[tid]=0.f;
  __syncthreads();

  const size_t p = (size_t)blockIdx.x*256 + tid;
  const float* xg = ws + OFF_XG;
  float x[6];
  #pragma unroll
  for (int c=0;c<6;c++) x[c] = xg[(size_t)c*MPTS + p];

  float h1[64];
  #pragma unroll
  for (int o=0;o<64;o++) h1[o] = sb1[o];

  for (int c=0;c<64;c++){
    const float4 wa = *reinterpret_cast<const float4*>(&sw0[c*8]);
    const float2 wb = *reinterpret_cast<const float2*>(&sw0[c*8+4]);
    float y = sb0[c];
    y = fmaf(wa.x,x[0],y); y = fmaf(wa.y,x[1],y); y = fmaf(wa.z,x[2],y);
    y = fmaf(wa.w,x[3],y); y = fmaf(wb.x,x[4],y); y = fmaf(wb.y,x[5],y);
    const float h = fmaxf(fmaf(ssc0[c], y, ssh0[c]), 0.f);
    const float4* wr = reinterpret_cast<const float4*>(&sw1T[c*64]);
    #pragma unroll
    for (int qq=0;qq<16;qq++){
      float4 wvv = wr[qq];
      h1[qq*4+0] = fmaf(wvv.x,h,h1[qq*4+0]);
      h1[qq*4+1] = fmaf(wvv.y,h,h1[qq*4+1]);
      h1[qq*4+2] = fmaf(wvv.z,h,h1[qq*4+2]);
      h1[qq*4+3] = fmaf(wvv.w,h,h1[qq*4+3]);
    }
  }
  #pragma unroll
  for (int o=0;o<64;o++) h1[o] = fmaxf(fmaf(ssc1[o], h1[o], ssh1[o]), 0.f);

  const int lane = tid & 63;
  const int l32  = tid & 31;
  const size_t gidx = p >> 5;
  float* maxb = ws + OFF_MAXB;
  float* minb = ws + OFF_MINB;

  for (int oc=0; oc<8; ++oc){
    float a[16];
    #pragma unroll
    for (int j=0;j<16;j++) a[j] = sb2[oc*16+j];
    for (int c=0;c<64;c++){
      const float4* wr = reinterpret_cast<const float4*>(&sw2T[c*128 + oc*16]);
      const float h = h1[c];
      #pragma unroll
      for (int qq=0;qq<4;qq++){
        float4 wvv = wr[qq];
        a[qq*4+0] = fmaf(wvv.x,h,a[qq*4+0]);
        a[qq*4+1] = fmaf(wvv.y,h,a[qq*4+1]);
        a[qq*4+2] = fmaf(wvv.z,h,a[qq*4+2]);
        a[qq*4+3] = fmaf(wvv.w,h,a[qq*4+3]);
      }
    }
    #pragma unroll
    for (int j=0;j<16;j++){
      const int o = oc*16 + j;
      float sv = a[j], sq = a[j]*a[j];
      #pragma unroll
      for (int off=32; off>=1; off>>=1){
        sv += __shfl_xor(sv,off,64);
        sq += __shfl_xor(sq,off,64);
      }
      if (lane == (o & 63)){
        atomicAdd(&red[o],     sv);
        atomicAdd(&red[128+o], sq);
      }
      float mx = a[j], mn = a[j];
      #pragma unroll
      for (int off=16; off>=1; off>>=1){
        mx = fmaxf(mx, __shfl_xor(mx,off,64));
        mn = fminf(mn, __shfl_xor(mn,off,64));
      }
      if (l32 == (o & 31)){
        maxb[gidx*128 + o] = mx;
        minb[gidx*128 + o] = mn;
      }
    }
  }
  __syncthreads();
  atomicAdd(&ws[OFF_S2SUM + tid], red[tid]);
}

__global__ __launch_bounds__(256) void final_out_kernel(
    const float* __restrict__ g2, const float* __restrict__ t2,
    const float* __restrict__ ws, float* __restrict__ out)
{
  const int g = blockIdx.x*256 + threadIdx.x; // B*S*128 threads
  const int o = g & 127;
  const float Mf = (float)MPTS;
  float mean = ws[OFF_S2SUM+o] / Mf;
  float var  = ws[OFF_S2SQ+o] / Mf - mean*mean;
  float sc = g2[o] / sqrtf(var + EPSF);
  float sh = t2[o] - mean*sc;
  // relu(sc*y+sh) is monotone in y: use group max if sc>0 else group min
  float v = (sc > 0.f) ? ws[OFF_MAXB+g] : ws[OFF_MINB+g];
  out[BB*SS*3 + g] = fmaxf(fmaf(sc, v, sh), 0.f);
}

extern "C" void kernel_launch(void* const* d_in, const int* in_sizes, int n_in,
                              void* d_out, int out_size, void* d_ws, size_t ws_size,
                              hipStream_t stream)
{
  const float* xyz = (const float*)d_in[0];
  const float* pts = (const float*)d_in[1];
  const int*   fps = (const int*)d_in[2];
  const float* w0  = (const float*)d_in[3];
  const float* b0  = (const float*)d_in[4];
  const float* g0  = (const float*)d_in[5];
  const float* t0  = (const float*)d_in[6];
  const float* w1  = (const float*)d_in[7];
  const float* b1  = (const float*)d_in[8];
  const float* g1  = (const float*)d_in[9];
  const float* t1  = (const float*)d_in[10];
  const float* w2  = (const float*)d_in[11];
  const float* b2  = (const float*)d_in[12];
  const float* g2  = (const float*)d_in[13];
  const float* t2  = (const float*)d_in[14];
  float* out = (float*)d_out;
  float* ws  = (float*)d_ws;

  hipMemsetAsync((void*)(ws + OFF_ST), 0, 512*sizeof(float), stream);
  prep_kernel<<<320,256,0,stream>>>(xyz, fps, out, ws);
  knn_group_kernel<<<BB*SS,256,0,stream>>>(pts, ws);
  finalize0_kernel<<<1,64,0,stream>>>(w0,b0,g0,t0,ws);
  layer1_stats_kernel<<<MPTS/256,256,0,stream>>>(w0,b0,w1,b1,ws);
  finalize1_kernel<<<1,64,0,stream>>>(g1,t1,ws);
  layer2_max_kernel<<<MPTS/256,256,0,stream>>>(w0,b0,w1,b1,w2,b2,ws);
  final_out_kernel<<<(BB*SS*128)/256,256,0,stream>>>(g2,t2,ws,out);
}

// Round 4
// 18286.189 us; speedup vs baseline: 1.0711x; 1.0006x over previous
//
#include <hip/hip_runtime.h>

#define BB 16
#define NN 4096
#define SS 1024
#define KK 32
#define MPTS (BB*SS*KK)      // 524288
#define EPSF 1e-5f

// workspace layout (float offsets)
#define OFF_QP    0                       // B*S*4  (qx,qy,qz,q2)
#define OFF_P4    (OFF_QP + BB*SS*4)      // B*N*4  (x,y,z,x2)
#define OFF_ST    (OFF_P4 + BB*NN*4)      // 512 floats, zeroed each call
#define OFF_MOM   (OFF_ST)                // 27
#define OFF_S1SUM (OFF_ST+32)             // 64
#define OFF_S1SQ  (OFF_ST+96)             // 64
#define OFF_S2SUM (OFF_ST+160)            // 128
#define OFF_S2SQ  (OFF_ST+288)            // 128
#define OFF_SC0   (OFF_ST+512)
#define OFF_SH0   (OFF_SC0+64)
#define OFF_SC1   (OFF_SH0+64)
#define OFF_SH1   (OFF_SC1+64)
#define OFF_XG    (OFF_SH1+64)            // 6*MPTS channel-major
#define OFF_MAXB  (OFF_XG + 6*MPTS)       // B*S*128
#define OFF_MINB  (OFF_MAXB + BB*SS*128)  // B*S*128

__global__ __launch_bounds__(256) void prep_kernel(
    const float* __restrict__ xyz, const int* __restrict__ fps,
    float* __restrict__ out, float* __restrict__ ws)
{
  const int g = blockIdx.x*256 + threadIdx.x;
  if (g < BB*NN){
    const float* p = xyz + (size_t)g*3;
    float x=p[0], y=p[1], z=p[2];
    float x2 = __fadd_rn(__fadd_rn(__fmul_rn(x,x),__fmul_rn(y,y)),__fmul_rn(z,z));
    *reinterpret_cast<float4*>(ws + OFF_P4 + (size_t)g*4) = make_float4(x,y,z,x2);
  } else {
    int j = g - BB*NN;
    if (j < BB*SS){
      int b = j >> 10;
      int idx = fps[j];
      const float* p = xyz + ((size_t)b*NN + idx)*3;
      float x=p[0], y=p[1], z=p[2];
      out[(size_t)j*3+0]=x; out[(size_t)j*3+1]=y; out[(size_t)j*3+2]=z;
      float q2 = __fadd_rn(__fadd_rn(__fmul_rn(x,x),__fmul_rn(y,y)),__fmul_rn(z,z));
      *reinterpret_cast<float4*>(ws + OFF_QP + (size_t)j*4) = make_float4(x,y,z,q2);
    }
  }
}

// one block per query: exact 32-NN via radix-select on orderable float bits.
// Histogram uses ballot-leader counting (no same-address LDS atomic storms).
__global__ __launch_bounds__(256) void knn_group_kernel(
    const float* __restrict__ pts, float* __restrict__ ws)
{
  __shared__ unsigned keys[NN];
  __shared__ unsigned hist[256];
  __shared__ unsigned wsum[4];
  __shared__ unsigned sh_bin, sh_knew;
  __shared__ int sh_nlt, sh_neq;
  __shared__ int sel[KK];
  __shared__ int eqlist[256];

  const int bid = blockIdx.x;
  const int b = bid >> 10;
  const int tid = threadIdx.x;
  const int lane = tid & 63;
  const int wv = tid >> 6;

  const float4 q = *reinterpret_cast<const float4*>(ws + OFF_QP + (size_t)bid*4);
  const float qx=q.x, qy=q.y, qz=q.z, q2=q.w;
  const float4* pb = reinterpret_cast<const float4*>(ws + OFF_P4) + (size_t)b*NN;

  #pragma unroll
  for (int j=0;j<16;j++){
    int n = tid + j*256;
    float4 P = pb[n];
    float dot = __fadd_rn(__fadd_rn(__fmul_rn(qx,P.x),__fmul_rn(qy,P.y)),__fmul_rn(qz,P.z));
    float d = __fsub_rn(__fadd_rn(q2, P.w), __fmul_rn(2.0f,dot));
    unsigned u = __float_as_uint(d);
    keys[n] = u ^ (unsigned)(((int)u>>31) | (int)0x80000000);
  }
  __syncthreads();

  const unsigned long long mlt = (lane==0) ? 0ull : (~0ull >> (64-lane));
  unsigned prefix = 0;
  int kk = KK;
  for (int pass=3; pass>=0; --pass){
    const int shift = pass*8;
    const unsigned maskhi = (pass==3) ? 0u : (0xFFFFFFFFu << (shift+8));
    hist[tid] = 0;
    __syncthreads();
    #pragma unroll
    for (int j=0;j<16;j++){
      unsigned key = keys[tid + j*256];
      bool act = ((key & maskhi) == prefix);
      if (__any((int)act)){
        unsigned bin = (key>>shift)&0xFFu;
        unsigned long long m = __ballot((int)act);
        #pragma unroll
        for (int bit=0;bit<8;bit++){
          unsigned long long bb = __ballot((int)(act && ((bin>>bit)&1u)));
          m &= ((bin>>bit)&1u) ? bb : ~bb;
        }
        if (act && (m & mlt) == 0ull)
          atomicAdd(&hist[bin], (unsigned)__popcll(m));
      }
    }
    __syncthreads();
    unsigned orig = hist[tid];
    unsigned v = orig;
    #pragma unroll
    for (int off=1; off<64; off<<=1){
      unsigned u = __shfl_up(v, (unsigned)off, 64);
      if (lane >= off) v += u;
    }
    if (lane==63) wsum[wv] = v;
    __syncthreads();
    unsigned add = 0;
    #pragma unroll
    for (int k=0;k<3;k++) if (wv > k) add += wsum[k];
    unsigned cumt = v + add;
    unsigned lower = cumt - orig;
    if (cumt >= (unsigned)kk && lower < (unsigned)kk){
      sh_bin = (unsigned)tid; sh_knew = (unsigned)kk - lower;
    }
    __syncthreads();
    prefix |= (sh_bin << shift);
    kk = (int)sh_knew;
  }
  const unsigned v32 = prefix;

  if (tid==0){ sh_nlt = 0; sh_neq = 0; }
  __syncthreads();
  #pragma unroll
  for (int j=0;j<16;j++){
    int n = tid + j*256;
    unsigned key = keys[n];
    if (key < v32){ int p = atomicAdd(&sh_nlt,1); sel[p] = n; }
    else if (key == v32){ int p = atomicAdd(&sh_neq,1); if (p < 256) eqlist[p] = n; }
  }
  __syncthreads();
  if (tid==0){
    int nlt = sh_nlt;
    int need = KK - nlt;
    int neq = sh_neq;
    if (neq <= 256){
      for (int a=0;a<need;a++){          // lowest-index ties first (top_k semantics)
        int mi = a;
        for (int c=a+1;c<neq;c++) if (eqlist[c] < eqlist[mi]) mi = c;
        int t = eqlist[a]; eqlist[a]=eqlist[mi]; eqlist[mi]=t;
        sel[nlt+a] = eqlist[a];
      }
    } else {
      int got = 0;
      for (int n=0;n<NN && got<need;n++) if (keys[n]==v32){ sel[nlt+got]=n; ++got; }
    }
  }
  __syncthreads();

  if (tid < KK){
    int n = sel[tid];
    float4 P = pb[n];
    float v6[6];
    v6[0] = P.x-qx; v6[1] = P.y-qy; v6[2] = P.z-qz;
    const float* pt = pts + ((size_t)b*NN + n)*3;
    v6[3] = pt[0]; v6[4] = pt[1]; v6[5] = pt[2];
    size_t pidx = (size_t)bid*KK + tid;
    float* xg = ws + OFF_XG;
    #pragma unroll
    for (int c=0;c<6;c++) xg[(size_t)c*MPTS + pidx] = v6[c];
    // layer-0 input moments (6 sums + 21 upper-tri products)
    float m[27];
    int mi = 0;
    #pragma unroll
    for (int c=0;c<6;c++) m[mi++] = v6[c];
    #pragma unroll
    for (int c=0;c<6;c++){
      #pragma unroll
      for (int c2=c;c2<6;c2++) m[mi++] = v6[c]*v6[c2];
    }
    #pragma unroll
    for (int off=16; off>=1; off>>=1){
      #pragma unroll
      for (int qq=0;qq<27;qq++) m[qq] += __shfl_xor(m[qq], off, 64);
    }
    if (tid==0){
      float* mom = ws + OFF_MOM;
      #pragma unroll
      for (int qq=0;qq<27;qq++) atomicAdd(&mom[qq], m[qq]);
    }
  }
}

__global__ void finalize0_kernel(const float* __restrict__ w0, const float* __restrict__ b0,
                                 const float* __restrict__ g0, const float* __restrict__ t0,
                                 float* __restrict__ ws)
{
  int o = threadIdx.x; // 64 threads
  const float* mom = ws + OFF_MOM;
  float w[6];
  #pragma unroll
  for (int c=0;c<6;c++) w[c] = w0[o*6+c];
  float bo = b0[o];
  float wS = 0.f;
  #pragma unroll
  for (int c=0;c<6;c++) wS += w[c]*mom[c];
  const float Mf = (float)MPTS;
  float mean = (wS + Mf*bo) / Mf;
  float qsum = 0.f;
  int mi = 6;
  #pragma unroll
  for (int c=0;c<6;c++){
    #pragma unroll
    for (int c2=c;c2<6;c2++){
      float f = (c==c2)?1.f:2.f;
      qsum += f * w[c]*w[c2]*mom[mi];
      mi++;
    }
  }
  float E2  = (qsum + 2.f*bo*wS + Mf*bo*bo) / Mf;
  float var = E2 - mean*mean;
  float sc  = g0[o] / sqrtf(var + EPSF);
  ws[OFF_SC0+o] = sc;
  ws[OFF_SH0+o] = t0[o] - mean*sc;
}

// per thread one point: h0_c on the fly (c-outer), accumulate y1 into acc[64].
__global__ __launch_bounds__(256,2) void layer1_stats_kernel(
    const float* __restrict__ w0g, const float* __restrict__ b0g,
    const float* __restrict__ w1g, const float* __restrict__ b1g,
    float* __restrict__ ws)
{
  __shared__ float sw0[64*8];    // padded rows: w0[c][0..5] at c*8
  __shared__ float sw1T[4096];   // [c][o]
  __shared__ float sb0[64], ssc0[64], ssh0[64], sb1[64];
  __shared__ float red[128];
  const int tid = threadIdx.x;
  for (int i=tid;i<384;i+=256){ int o=i/6, c=i-o*6; sw0[o*8+c] = w0g[i]; }
  for (int i=tid;i<4096;i+=256){ int o=i>>6, c=i&63; sw1T[c*64+o] = w1g[i]; }
  if (tid<64){ sb0[tid]=b0g[tid]; sb1[tid]=b1g[tid];
               ssc0[tid]=ws[OFF_SC0+tid]; ssh0[tid]=ws[OFF_SH0+tid]; }
  if (tid<128) red[tid]=0.f;
  __syncthreads();

  const size_t p = (size_t)blockIdx.x*256 + tid;
  const float* xg = ws + OFF_XG;
  float x[6];
  #pragma unroll
  for (int c=0;c<6;c++) x[c] = xg[(size_t)c*MPTS + p];

  float acc[64];
  #pragma unroll
  for (int o=0;o<64;o++) acc[o] = sb1[o];

  for (int c=0;c<64;c++){
    const float4 wa = *reinterpret_cast<const float4*>(&sw0[c*8]);
    const float2 wb = *reinterpret_cast<const float2*>(&sw0[c*8+4]);
    float y = sb0[c];
    y = fmaf(wa.x,x[0],y); y = fmaf(wa.y,x[1],y); y = fmaf(wa.z,x[2],y);
    y = fmaf(wa.w,x[3],y); y = fmaf(wb.x,x[4],y); y = fmaf(wb.y,x[5],y);
    const float h = fmaxf(fmaf(ssc0[c], y, ssh0[c]), 0.f);
    const float4* wr = reinterpret_cast<const float4*>(&sw1T[c*64]);
    #pragma unroll
    for (int qq=0;qq<16;qq++){
      float4 wvv = wr[qq];
      acc[qq*4+0] = fmaf(wvv.x,h,acc[qq*4+0]);
      acc[qq*4+1] = fmaf(wvv.y,h,acc[qq*4+1]);
      acc[qq*4+2] = fmaf(wvv.z,h,acc[qq*4+2]);
      acc[qq*4+3] = fmaf(wvv.w,h,acc[qq*4+3]);
    }
  }
  const int lane = tid & 63;
  #pragma unroll
  for (int o=0;o<64;o++){
    float sv = acc[o];
    float sq = acc[o]*acc[o];
    #pragma unroll
    for (int off=32; off>=1; off>>=1){
      sv += __shfl_xor(sv, off, 64);
      sq += __shfl_xor(sq, off, 64);
    }
    if (lane == o){
      atomicAdd(&red[o],    sv);
      atomicAdd(&red[64+o], sq);
    }
  }
  __syncthreads();
  if (tid < 128) atomicAdd(&ws[OFF_S1SUM + tid], red[tid]);
}

__global__ void finalize1_kernel(const float* __restrict__ g1, const float* __restrict__ t1,
                                 float* __restrict__ ws)
{
  int o = threadIdx.x;
  const float Mf = (float)MPTS;
  float mean = ws[OFF_S1SUM+o]/Mf;
  float var  = ws[OFF_S1SQ+o]/Mf - mean*mean;
  float sc = g1[o]/sqrtf(var+EPSF);
  ws[OFF_SC1+o]=sc; ws[OFF_SH1+o]=t1[o]-mean*sc;
}

// full chain per point: h1 via c-outer acc, then y2 in 8 chunks of 16 channels.
// NOTE: every loop that reads h1[c] with loop-carried c MUST be fully unrolled
// (rule: runtime-indexed register arrays are demoted to scratch).
__global__ __launch_bounds__(256,2) void layer2_max_kernel(
    const float* __restrict__ w0g, const float* __restrict__ b0g,
    const float* __restrict__ w1g, const float* __restrict__ b1g,
    const float* __restrict__ w2g, const float* __restrict__ b2g,
    float* __restrict__ ws)
{
  __shared__ float sw0[64*8];
  __shared__ float sw1T[4096];   // [c][o] 64x64
  __shared__ float sw2T[8192];   // [c][o] 64x128
  __shared__ float sb0[64], ssc0[64], ssh0[64], sb1[64], ssc1[64], ssh1[64], sb2[128];
  __shared__ float red[256];
  const int tid = threadIdx.x;
  for (int i=tid;i<384;i+=256){ int o=i/6, c=i-o*6; sw0[o*8+c] = w0g[i]; }
  for (int i=tid;i<4096;i+=256){ int o=i>>6, c=i&63; sw1T[c*64+o] = w1g[i]; }
  for (int i=tid;i<8192;i+=256){ int o=i>>6, c=i&63; sw2T[c*128+o] = w2g[i]; }
  if (tid<64){ sb0[tid]=b0g[tid]; sb1[tid]=b1g[tid];
               ssc0[tid]=ws[OFF_SC0+tid]; ssh0[tid]=ws[OFF_SH0+tid];
               ssc1[tid]=ws[OFF_SC1+tid]; ssh1[tid]=ws[OFF_SH1+tid]; }
  if (tid<128) sb2[tid]=b2g[tid];
  red[tid]=0.f;
  __syncthreads();

  const size_t p = (size_t)blockIdx.x*256 + tid;
  const float* xg = ws + OFF_XG;
  float x[6];
  #pragma unroll
  for (int c=0;c<6;c++) x[c] = xg[(size_t)c*MPTS + p];

  float h1[64];
  #pragma unroll
  for (int o=0;o<64;o++) h1[o] = sb1[o];

  for (int c=0;c<64;c++){
    const float4 wa = *reinterpret_cast<const float4*>(&sw0[c*8]);
    const float2 wb = *reinterpret_cast<const float2*>(&sw0[c*8+4]);
    float y = sb0[c];
    y = fmaf(wa.x,x[0],y); y = fmaf(wa.y,x[1],y); y = fmaf(wa.z,x[2],y);
    y = fmaf(wa.w,x[3],y); y = fmaf(wb.x,x[4],y); y = fmaf(wb.y,x[5],y);
    const float h = fmaxf(fmaf(ssc0[c], y, ssh0[c]), 0.f);
    const float4* wr = reinterpret_cast<const float4*>(&sw1T[c*64]);
    #pragma unroll
    for (int qq=0;qq<16;qq++){
      float4 wvv = wr[qq];
      h1[qq*4+0] = fmaf(wvv.x,h,h1[qq*4+0]);
      h1[qq*4+1] = fmaf(wvv.y,h,h1[qq*4+1]);
      h1[qq*4+2] = fmaf(wvv.z,h,h1[qq*4+2]);
      h1[qq*4+3] = fmaf(wvv.w,h,h1[qq*4+3]);
    }
  }
  #pragma unroll
  for (int o=0;o<64;o++) h1[o] = fmaxf(fmaf(ssc1[o], h1[o], ssh1[o]), 0.f);

  const int lane = tid & 63;
  const int l32  = tid & 31;
  const size_t gidx = p >> 5;
  float* maxb = ws + OFF_MAXB;
  float* minb = ws + OFF_MINB;

  for (int oc=0; oc<8; ++oc){
    float a[16];
    #pragma unroll
    for (int j=0;j<16;j++) a[j] = sb2[oc*16+j];
    #pragma unroll
    for (int c=0;c<64;c++){                 // MUST stay unrolled: h1[c]
      const float4* wr = reinterpret_cast<const float4*>(&sw2T[c*128 + oc*16]);
      const float h = h1[c];
      #pragma unroll
      for (int qq=0;qq<4;qq++){
        float4 wvv = wr[qq];
        a[qq*4+0] = fmaf(wvv.x,h,a[qq*4+0]);
        a[qq*4+1] = fmaf(wvv.y,h,a[qq*4+1]);
        a[qq*4+2] = fmaf(wvv.z,h,a[qq*4+2]);
        a[qq*4+3] = fmaf(wvv.w,h,a[qq*4+3]);
      }
    }
    #pragma unroll
    for (int j=0;j<16;j++){
      const int o = oc*16 + j;
      float sv = a[j], sq = a[j]*a[j];
      #pragma unroll
      for (int off=32; off>=1; off>>=1){
        sv += __shfl_xor(sv,off,64);
        sq += __shfl_xor(sq,off,64);
      }
      if (lane == (o & 63)){
        atomicAdd(&red[o],     sv);
        atomicAdd(&red[128+o], sq);
      }
      float mx = a[j], mn = a[j];
      #pragma unroll
      for (int off=16; off>=1; off>>=1){
        mx = fmaxf(mx, __shfl_xor(mx,off,64));
        mn = fminf(mn, __shfl_xor(mn,off,64));
      }
      if (l32 == (o & 31)){
        maxb[gidx*128 + o] = mx;
        minb[gidx*128 + o] = mn;
      }
    }
  }
  __syncthreads();
  atomicAdd(&ws[OFF_S2SUM + tid], red[tid]);
}

__global__ __launch_bounds__(256) void final_out_kernel(
    const float* __restrict__ g2, const float* __restrict__ t2,
    const float* __restrict__ ws, float* __restrict__ out)
{
  const int g = blockIdx.x*256 + threadIdx.x; // B*S*128 threads
  const int o = g & 127;
  const float Mf = (float)MPTS;
  float mean = ws[OFF_S2SUM+o] / Mf;
  float var  = ws[OFF_S2SQ+o] / Mf - mean*mean;
  float sc = g2[o] / sqrtf(var + EPSF);
  float sh = t2[o] - mean*sc;
  // relu(sc*y+sh) is monotone in y: use group max if sc>0 else group min
  float v = (sc > 0.f) ? ws[OFF_MAXB+g] : ws[OFF_MINB+g];
  out[BB*SS*3 + g] = fmaxf(fmaf(sc, v, sh), 0.f);
}

extern "C" void kernel_launch(void* const* d_in, const int* in_sizes, int n_in,
                              void* d_out, int out_size, void* d_ws, size_t ws_size,
                              hipStream_t stream)
{
  const float* xyz = (const float*)d_in[0];
  const float* pts = (const float*)d_in[1];
  const int*   fps = (const int*)d_in[2];
  const float* w0  = (const float*)d_in[3];
  const float* b0  = (const float*)d_in[4];
  const float* g0  = (const float*)d_in[5];
  const float* t0  = (const float*)d_in[6];
  const float* w1  = (const float*)d_in[7];
  const float* b1  = (const float*)d_in[8];
  const float* g1  = (const float*)d_in[9];
  const float* t1  = (const float*)d_in[10];
  const float* w2  = (const float*)d_in[11];
  const float* b2  = (const float*)d_in[12];
  const float* g2  = (const float*)d_in[13];
  const float* t2  = (const float*)d_in[14];
  float* out = (float*)d_out;
  float* ws  = (float*)d_ws;

  hipMemsetAsync((void*)(ws + OFF_ST), 0, 512*sizeof(float), stream);
  prep_kernel<<<320,256,0,stream>>>(xyz, fps, out, ws);
  knn_group_kernel<<<BB*SS,256,0,stream>>>(pts, ws);
  finalize0_kernel<<<1,64,0,stream>>>(w0,b0,g0,t0,ws);
  layer1_stats_kernel<<<MPTS/256,256,0,stream>>>(w0,b0,w1,b1,ws);
  finalize1_kernel<<<1,64,0,stream>>>(g1,t1,ws);
  layer2_max_kernel<<<MPTS/256,256,0,stream>>>(w0,b0,w1,b1,w2,b2,ws);
  final_out_kernel<<<(BB*SS*128)/256,256,0,stream>>>(g2,t2,ws,out);
}

// Round 5
// 4060.696 us; speedup vs baseline: 4.8234x; 4.5032x over previous
//
#include <hip/hip_runtime.h>

#define BB 16
#define NN 4096
#define SS 1024
#define KK 32
#define MPTS (BB*SS*KK)      // 524288
#define EPSF 1e-5f

// workspace layout (float offsets)
#define OFF_QP    0                       // B*S*4
#define OFF_P4    (OFF_QP + BB*SS*4)      // B*N*4
#define OFF_ST    (OFF_P4 + BB*NN*4)      // 512 floats zeroed each call
#define OFF_MOM   (OFF_ST)                // 27
#define OFF_S1SUM (OFF_ST+32)             // 64
#define OFF_S1SQ  (OFF_ST+96)             // 64
#define OFF_S2SUM (OFF_ST+160)            // 128
#define OFF_S2SQ  (OFF_ST+288)            // 128
#define OFF_SC0   (OFF_ST+512)
#define OFF_SH0   (OFF_SC0+64)
#define OFF_SC1   (OFF_SH0+64)
#define OFF_SH1   (OFF_SC1+64)
#define OFF_XG    (OFF_ST+1280)           // 6*MPTS channel-major
#define OFF_MAXB  (OFF_XG + 6*MPTS)       // B*S*128
#define OFF_MINB  (OFF_MAXB + BB*SS*128)  // B*S*128
#define OFF_Y1U   (OFF_MINB + BB*SS*128)  // bf16 (ushort) [64][MPTS] -> 67MB; total ~98MB

__global__ __launch_bounds__(256) void prep_kernel(
    const float* __restrict__ xyz, const int* __restrict__ fps,
    float* __restrict__ out, float* __restrict__ ws)
{
  const int g = blockIdx.x*256 + threadIdx.x;
  if (g < BB*NN){
    const float* p = xyz + (size_t)g*3;
    float x=p[0], y=p[1], z=p[2];
    float x2 = __fadd_rn(__fadd_rn(__fmul_rn(x,x),__fmul_rn(y,y)),__fmul_rn(z,z));
    *reinterpret_cast<float4*>(ws + OFF_P4 + (size_t)g*4) = make_float4(x,y,z,x2);
  } else {
    int j = g - BB*NN;
    if (j < BB*SS){
      int b = j >> 10;
      int idx = fps[j];
      const float* p = xyz + ((size_t)b*NN + idx)*3;
      float x=p[0], y=p[1], z=p[2];
      out[(size_t)j*3+0]=x; out[(size_t)j*3+1]=y; out[(size_t)j*3+2]=z;
      float q2 = __fadd_rn(__fadd_rn(__fmul_rn(x,x),__fmul_rn(y,y)),__fmul_rn(z,z));
      *reinterpret_cast<float4*>(ws + OFF_QP + (size_t)j*4) = make_float4(x,y,z,q2);
    }
  }
}

// one block per query: exact 32-NN via radix-select on orderable float bits.
__global__ __launch_bounds__(256) void knn_group_kernel(
    const float* __restrict__ pts, float* __restrict__ ws)
{
  __shared__ unsigned keys[NN];
  __shared__ unsigned hist[256];
  __shared__ unsigned wsum[4];
  __shared__ unsigned sh_bin, sh_knew;
  __shared__ int sh_nlt, sh_neq;
  __shared__ int sel[KK];
  __shared__ int eqlist[256];

  const int bid = blockIdx.x;
  const int b = bid >> 10;
  const int tid = threadIdx.x;
  const int lane = tid & 63;
  const int wv = tid >> 6;

  const float4 q = *reinterpret_cast<const float4*>(ws + OFF_QP + (size_t)bid*4);
  const float qx=q.x, qy=q.y, qz=q.z, q2=q.w;
  const float4* pb = reinterpret_cast<const float4*>(ws + OFF_P4) + (size_t)b*NN;

  #pragma unroll
  for (int j=0;j<16;j++){
    int n = tid + j*256;
    float4 P = pb[n];
    float dot = __fadd_rn(__fadd_rn(__fmul_rn(qx,P.x),__fmul_rn(qy,P.y)),__fmul_rn(qz,P.z));
    float d = __fsub_rn(__fadd_rn(q2, P.w), __fmul_rn(2.0f,dot));
    unsigned u = __float_as_uint(d);
    keys[n] = u ^ (unsigned)(((int)u>>31) | (int)0x80000000);
  }
  __syncthreads();

  const unsigned long long mlt = (lane==0) ? 0ull : (~0ull >> (64-lane));
  unsigned prefix = 0;
  int kk = KK;
  for (int pass=3; pass>=0; --pass){
    const int shift = pass*8;
    const unsigned maskhi = (pass==3) ? 0u : (0xFFFFFFFFu << (shift+8));
    hist[tid] = 0;
    __syncthreads();
    #pragma unroll
    for (int j=0;j<16;j++){
      unsigned key = keys[tid + j*256];
      bool act = ((key & maskhi) == prefix);
      if (__any((int)act)){
        unsigned bin = (key>>shift)&0xFFu;
        unsigned long long m = __ballot((int)act);
        #pragma unroll
        for (int bit=0;bit<8;bit++){
          unsigned long long bb = __ballot((int)(act && ((bin>>bit)&1u)));
          m &= ((bin>>bit)&1u) ? bb : ~bb;
        }
        if (act && (m & mlt) == 0ull)
          atomicAdd(&hist[bin], (unsigned)__popcll(m));
      }
    }
    __syncthreads();
    unsigned orig = hist[tid];
    unsigned v = orig;
    #pragma unroll
    for (int off=1; off<64; off<<=1){
      unsigned u = __shfl_up(v, (unsigned)off, 64);
      if (lane >= off) v += u;
    }
    if (lane==63) wsum[wv] = v;
    __syncthreads();
    unsigned add = 0;
    #pragma unroll
    for (int k=0;k<3;k++) if (wv > k) add += wsum[k];
    unsigned cumt = v + add;
    unsigned lower = cumt - orig;
    if (cumt >= (unsigned)kk && lower < (unsigned)kk){
      sh_bin = (unsigned)tid; sh_knew = (unsigned)kk - lower;
    }
    __syncthreads();
    prefix |= (sh_bin << shift);
    kk = (int)sh_knew;
  }
  const unsigned v32 = prefix;

  if (tid==0){ sh_nlt = 0; sh_neq = 0; }
  __syncthreads();
  #pragma unroll
  for (int j=0;j<16;j++){
    int n = tid + j*256;
    unsigned key = keys[n];
    if (key < v32){ int p = atomicAdd(&sh_nlt,1); sel[p] = n; }
    else if (key == v32){ int p = atomicAdd(&sh_neq,1); if (p < 256) eqlist[p] = n; }
  }
  __syncthreads();
  if (tid==0){
    int nlt = sh_nlt;
    int need = KK - nlt;
    int neq = sh_neq;
    if (neq <= 256){
      for (int a=0;a<need;a++){          // lowest-index ties first (top_k semantics)
        int mi = a;
        for (int c=a+1;c<neq;c++) if (eqlist[c] < eqlist[mi]) mi = c;
        int t = eqlist[a]; eqlist[a]=eqlist[mi]; eqlist[mi]=t;
        sel[nlt+a] = eqlist[a];
      }
    } else {
      int got = 0;
      for (int n=0;n<NN && got<need;n++) if (keys[n]==v32){ sel[nlt+got]=n; ++got; }
    }
  }
  __syncthreads();

  if (tid < KK){
    int n = sel[tid];
    float4 P = pb[n];
    float v6[6];
    v6[0] = P.x-qx; v6[1] = P.y-qy; v6[2] = P.z-qz;
    const float* pt = pts + ((size_t)b*NN + n)*3;
    v6[3] = pt[0]; v6[4] = pt[1]; v6[5] = pt[2];
    size_t pidx = (size_t)bid*KK + tid;
    float* xg = ws + OFF_XG;
    #pragma unroll
    for (int c=0;c<6;c++) xg[(size_t)c*MPTS + pidx] = v6[c];
    // layer-0 input moments (6 sums + 21 upper-tri products)
    float m[27];
    int mi = 0;
    #pragma unroll
    for (int c=0;c<6;c++) m[mi++] = v6[c];
    #pragma unroll
    for (int c=0;c<6;c++){
      #pragma unroll
      for (int c2=c;c2<6;c2++) m[mi++] = v6[c]*v6[c2];
    }
    #pragma unroll
    for (int off=16; off>=1; off>>=1){
      #pragma unroll
      for (int qq=0;qq<27;qq++) m[qq] += __shfl_xor(m[qq], off, 64);
    }
    if (tid==0){
      float* mom = ws + OFF_MOM;
      #pragma unroll
      for (int qq=0;qq<27;qq++) atomicAdd(&mom[qq], m[qq]);
    }
  }
}

__global__ void finalize0_kernel(const float* __restrict__ w0, const float* __restrict__ b0,
                                 const float* __restrict__ g0, const float* __restrict__ t0,
                                 float* __restrict__ ws)
{
  int o = threadIdx.x; // 64 threads
  const float* mom = ws + OFF_MOM;
  float w[6];
  #pragma unroll
  for (int c=0;c<6;c++) w[c] = w0[o*6+c];
  float bo = b0[o];
  float wS = 0.f;
  #pragma unroll
  for (int c=0;c<6;c++) wS += w[c]*mom[c];
  const float Mf = (float)MPTS;
  float mean = (wS + Mf*bo) / Mf;
  float qsum = 0.f;
  int mi = 6;
  #pragma unroll
  for (int c=0;c<6;c++){
    #pragma unroll
    for (int c2=c;c2<6;c2++){
      float f = (c==c2)?1.f:2.f;
      qsum += f * w[c]*w[c2]*mom[mi];
      mi++;
    }
  }
  float E2  = (qsum + 2.f*bo*wS + Mf*bo*bo) / Mf;
  float var = E2 - mean*mean;
  float sc  = g0[o] / sqrtf(var + EPSF);
  ws[OFF_SC0+o] = sc;
  ws[OFF_SH0+o] = t0[o] - mean*sc;
}

// thread = point: recompute h0 per channel on the fly, accumulate y1 in two
// chunks of 32 (a[32] only live array), store raw y1 as bf16 channel-major.
__global__ __launch_bounds__(256) void l1_kernel(
    const float* __restrict__ w0g, const float* __restrict__ b0g,
    const float* __restrict__ w1g, const float* __restrict__ b1g,
    float* __restrict__ ws)
{
  __shared__ float sw0[64*8];    // w0[c][0..5] at c*8
  __shared__ float sw1T[4096];   // [c][o]
  __shared__ float sb0[64], ssc0[64], ssh0[64], sb1[64];
  const int tid = threadIdx.x;
  for (int i=tid;i<384;i+=256){ int o=i/6, c=i-o*6; sw0[o*8+c] = w0g[i]; }
  // transpose on the global-read side: LDS writes are consecutive (no conflicts)
  for (int i=tid;i<4096;i+=256){ int c=i>>6, o=i&63; sw1T[c*64+o] = w1g[o*64+c]; }
  if (tid<64){ sb0[tid]=b0g[tid]; sb1[tid]=b1g[tid];
               ssc0[tid]=ws[OFF_SC0+tid]; ssh0[tid]=ws[OFF_SH0+tid]; }
  __syncthreads();

  const size_t p = (size_t)blockIdx.x*256 + tid;
  const float* xg = ws + OFF_XG;
  const float x0=xg[p],        x1=xg[MPTS+p],   x2=xg[2ul*MPTS+p];
  const float x3=xg[3ul*MPTS+p], x4=xg[4ul*MPTS+p], x5=xg[5ul*MPTS+p];
  unsigned short* y1 = (unsigned short*)(ws + OFF_Y1U);

  for (int ch=0; ch<2; ++ch){
    float a[32];
    #pragma unroll
    for (int j=0;j<32;j++) a[j] = sb1[ch*32+j];
    for (int c=0;c<64;c++){
      const float4 wa = *reinterpret_cast<const float4*>(&sw0[c*8]);
      const float2 wb = *reinterpret_cast<const float2*>(&sw0[c*8+4]);
      float y = sb0[c];
      y = fmaf(wa.x,x0,y); y = fmaf(wa.y,x1,y); y = fmaf(wa.z,x2,y);
      y = fmaf(wa.w,x3,y); y = fmaf(wb.x,x4,y); y = fmaf(wb.y,x5,y);
      const float h = fmaxf(fmaf(ssc0[c], y, ssh0[c]), 0.f);
      const float4* wr = reinterpret_cast<const float4*>(&sw1T[c*64 + ch*32]);
      #pragma unroll
      for (int qq=0;qq<8;qq++){
        float4 wvv = wr[qq];
        a[qq*4+0] = fmaf(wvv.x,h,a[qq*4+0]);
        a[qq*4+1] = fmaf(wvv.y,h,a[qq*4+1]);
        a[qq*4+2] = fmaf(wvv.z,h,a[qq*4+2]);
        a[qq*4+3] = fmaf(wvv.w,h,a[qq*4+3]);
      }
    }
    #pragma unroll
    for (int j=0;j<32;j++){
      unsigned u = __float_as_uint(a[j]);
      u = (u + 0x7FFFu + ((u>>16)&1u)) >> 16;   // RNE f32->bf16
      y1[(size_t)(ch*32+j)*MPTS + p] = (unsigned short)u;
    }
  }
}

// reduce per-channel sum/sumsq of y1 (bf16): 8 slice-blocks per channel
__global__ __launch_bounds__(256) void stats1_kernel(float* __restrict__ ws)
{
  const int c  = blockIdx.x >> 3;
  const int sl = blockIdx.x & 7;
  const unsigned short* y1 = (const unsigned short*)(ws + OFF_Y1U);
  const unsigned short* src = y1 + (size_t)c*MPTS + (size_t)sl*(MPTS/8);
  float sv=0.f, sq=0.f;
  for (int k=threadIdx.x; k<MPTS/8; k+=256){
    float v = __uint_as_float(((unsigned)src[k])<<16);
    sv += v; sq += v*v;
  }
  #pragma unroll
  for (int off=32; off>=1; off>>=1){
    sv += __shfl_xor(sv,off,64); sq += __shfl_xor(sq,off,64);
  }
  __shared__ float r[8];
  const int lane = threadIdx.x & 63, wv = threadIdx.x >> 6;
  if (lane==0){ r[wv]=sv; r[4+wv]=sq; }
  __syncthreads();
  if (threadIdx.x==0){
    atomicAdd(&ws[OFF_S1SUM+c], r[0]+r[1]+r[2]+r[3]);
    atomicAdd(&ws[OFF_S1SQ+c],  r[4]+r[5]+r[6]+r[7]);
  }
}

__global__ void finalize1_kernel(const float* __restrict__ g1, const float* __restrict__ t1,
                                 float* __restrict__ ws)
{
  int o = threadIdx.x;
  const float Mf = (float)MPTS;
  float mean = ws[OFF_S1SUM+o]/Mf;
  float var  = ws[OFF_S1SQ+o]/Mf - mean*mean;
  float sc = g1[o]/sqrtf(var+EPSF);
  ws[OFF_SC1+o]=sc; ws[OFF_SH1+o]=t1[o]-mean*sc;
}

// thread = point: h1_c read from global y1 (bf16) on the fly; y2 in 8 chunks
// of 16 channels (a[16] only live array); stats + per-group max/min of raw y2.
__global__ __launch_bounds__(256) void l2_kernel(
    const float* __restrict__ w2g, const float* __restrict__ b2g,
    float* __restrict__ ws)
{
  __shared__ float sw2T[8192];   // [c][o] 64x128
  __shared__ float sb2[128];
  __shared__ float s1c[64], s1h[64];
  __shared__ float red[256];
  const int tid = threadIdx.x;
  for (int i=tid;i<8192;i+=256){ int c=i>>7, o=i&127; sw2T[c*128+o] = w2g[o*64+c]; }
  if (tid<128) sb2[tid]=b2g[tid];
  if (tid<64){ s1c[tid]=ws[OFF_SC1+tid]; s1h[tid]=ws[OFF_SH1+tid]; }
  red[tid]=0.f;
  __syncthreads();

  const size_t p = (size_t)blockIdx.x*256 + tid;
  const unsigned short* y1 = (const unsigned short*)(ws + OFF_Y1U);
  const int lane = tid & 63;
  const int l32  = tid & 31;
  const size_t gidx = p >> 5;
  float* maxb = ws + OFF_MAXB;
  float* minb = ws + OFF_MINB;

  for (int oc=0; oc<8; ++oc){
    float a[16];
    #pragma unroll
    for (int j=0;j<16;j++) a[j] = sb2[oc*16+j];
    for (int c=0;c<64;c++){
      float v = __uint_as_float(((unsigned)y1[(size_t)c*MPTS + p])<<16);
      const float h = fmaxf(fmaf(s1c[c], v, s1h[c]), 0.f);
      const float4* wr = reinterpret_cast<const float4*>(&sw2T[c*128 + oc*16]);
      #pragma unroll
      for (int qq=0;qq<4;qq++){
        float4 wvv = wr[qq];
        a[qq*4+0] = fmaf(wvv.x,h,a[qq*4+0]);
        a[qq*4+1] = fmaf(wvv.y,h,a[qq*4+1]);
        a[qq*4+2] = fmaf(wvv.z,h,a[qq*4+2]);
        a[qq*4+3] = fmaf(wvv.w,h,a[qq*4+3]);
      }
    }
    #pragma unroll
    for (int j=0;j<16;j++){
      const int o = oc*16 + j;
      float sv = a[j], sq = a[j]*a[j];
      #pragma unroll
      for (int off=32; off>=1; off>>=1){
        sv += __shfl_xor(sv,off,64);
        sq += __shfl_xor(sq,off,64);
      }
      if (lane == (o & 63)){
        atomicAdd(&red[o],     sv);
        atomicAdd(&red[128+o], sq);
      }
      float mx = a[j], mn = a[j];
      #pragma unroll
      for (int off=16; off>=1; off>>=1){
        mx = fmaxf(mx, __shfl_xor(mx,off,64));
        mn = fminf(mn, __shfl_xor(mn,off,64));
      }
      if (l32 == (o & 31)){
        maxb[gidx*128 + o] = mx;
        minb[gidx*128 + o] = mn;
      }
    }
  }
  __syncthreads();
  atomicAdd(&ws[OFF_S2SUM + tid], red[tid]);
}

__global__ __launch_bounds__(256) void final_out_kernel(
    const float* __restrict__ g2, const float* __restrict__ t2,
    const float* __restrict__ ws, float* __restrict__ out)
{
  const int g = blockIdx.x*256 + threadIdx.x; // B*S*128 threads
  const int o = g & 127;
  const float Mf = (float)MPTS;
  float mean = ws[OFF_S2SUM+o] / Mf;
  float var  = ws[OFF_S2SQ+o] / Mf - mean*mean;
  float sc = g2[o] / sqrtf(var + EPSF);
  float sh = t2[o] - mean*sc;
  // relu(sc*y+sh) monotone in y: group max if sc>0 else group min
  float v = (sc > 0.f) ? ws[OFF_MAXB+g] : ws[OFF_MINB+g];
  out[BB*SS*3 + g] = fmaxf(fmaf(sc, v, sh), 0.f);
}

extern "C" void kernel_launch(void* const* d_in, const int* in_sizes, int n_in,
                              void* d_out, int out_size, void* d_ws, size_t ws_size,
                              hipStream_t stream)
{
  const float* xyz = (const float*)d_in[0];
  const float* pts = (const float*)d_in[1];
  const int*   fps = (const int*)d_in[2];
  const float* w0  = (const float*)d_in[3];
  const float* b0  = (const float*)d_in[4];
  const float* g0  = (const float*)d_in[5];
  const float* t0  = (const float*)d_in[6];
  const float* w1  = (const float*)d_in[7];
  const float* b1  = (const float*)d_in[8];
  const float* g1  = (const float*)d_in[9];
  const float* t1  = (const float*)d_in[10];
  const float* w2  = (const float*)d_in[11];
  const float* b2  = (const float*)d_in[12];
  const float* g2  = (const float*)d_in[13];
  const float* t2  = (const float*)d_in[14];
  float* out = (float*)d_out;
  float* ws  = (float*)d_ws;

  hipMemsetAsync((void*)(ws + OFF_ST), 0, 512*sizeof(float), stream);
  prep_kernel<<<320,256,0,stream>>>(xyz, fps, out, ws);
  knn_group_kernel<<<BB*SS,256,0,stream>>>(pts, ws);
  finalize0_kernel<<<1,64,0,stream>>>(w0,b0,g0,t0,ws);
  l1_kernel<<<MPTS/256,256,0,stream>>>(w0,b0,w1,b1,ws);
  stats1_kernel<<<512,256,0,stream>>>(ws);
  finalize1_kernel<<<1,64,0,stream>>>(g1,t1,ws);
  l2_kernel<<<MPTS/256,256,0,stream>>>(w2,b2,ws);
  final_out_kernel<<<(BB*SS*128)/256,256,0,stream>>>(g2,t2,ws,out);
}

// Round 6
// 4022.374 us; speedup vs baseline: 4.8694x; 1.0095x over previous
//
#include <hip/hip_runtime.h>

#define BB 16
#define NN 4096
#define SS 1024
#define KK 32
#define MPTS (BB*SS*KK)      // 524288
#define EPSF 1e-5f
#define CANDCAP 2048

// workspace layout (float offsets)
#define OFF_QP    0                       // B*S*4
#define OFF_P4    (OFF_QP + BB*SS*4)      // B*N*4
#define OFF_ST    (OFF_P4 + BB*NN*4)      // 512 floats zeroed each call
#define OFF_MOM   (OFF_ST)                // 27
#define OFF_S1SUM (OFF_ST+32)             // 64
#define OFF_S1SQ  (OFF_ST+96)             // 64
#define OFF_S2SUM (OFF_ST+160)            // 128
#define OFF_S2SQ  (OFF_ST+288)            // 128
#define OFF_SC0   (OFF_ST+512)
#define OFF_SH0   (OFF_SC0+64)
#define OFF_SC1   (OFF_SH0+64)
#define OFF_SH1   (OFF_SC1+64)
#define OFF_XG    (OFF_ST+1280)           // 6*MPTS channel-major
#define OFF_MAXB  (OFF_XG + 6*MPTS)       // B*S*128
#define OFF_MINB  (OFF_MAXB + BB*SS*128)  // B*S*128
#define OFF_Y1U   (OFF_MINB + BB*SS*128)  // bf16 (ushort) [64][MPTS] -> 67MB

__global__ __launch_bounds__(256) void prep_kernel(
    const float* __restrict__ xyz, const int* __restrict__ fps,
    float* __restrict__ out, float* __restrict__ ws)
{
  const int g = blockIdx.x*256 + threadIdx.x;
  if (g < BB*NN){
    const float* p = xyz + (size_t)g*3;
    float x=p[0], y=p[1], z=p[2];
    float x2 = __fadd_rn(__fadd_rn(__fmul_rn(x,x),__fmul_rn(y,y)),__fmul_rn(z,z));
    *reinterpret_cast<float4*>(ws + OFF_P4 + (size_t)g*4) = make_float4(x,y,z,x2);
  } else {
    int j = g - BB*NN;
    if (j < BB*SS){
      int b = j >> 10;
      int idx = fps[j];
      const float* p = xyz + ((size_t)b*NN + idx)*3;
      float x=p[0], y=p[1], z=p[2];
      out[(size_t)j*3+0]=x; out[(size_t)j*3+1]=y; out[(size_t)j*3+2]=z;
      float q2 = __fadd_rn(__fadd_rn(__fmul_rn(x,x),__fmul_rn(y,y)),__fmul_rn(z,z));
      *reinterpret_cast<float4*>(ws + OFF_QP + (size_t)j*4) = make_float4(x,y,z,q2);
    }
  }
}

// one block per query: exact 32-NN. Keys live in registers (unrolled).
// One top-byte histogram level (usually), then compact boundary-bin
// candidates as packed (key<<32|idx) and exact parallel rank-select.
__global__ __launch_bounds__(256) void knn_group_kernel(
    const float* __restrict__ pts, float* __restrict__ ws)
{
  __shared__ unsigned hist[256];
  __shared__ unsigned wsum[4];
  __shared__ unsigned long long cand[CANDCAP];
  __shared__ int sel[KK];
  __shared__ unsigned sh_b, sh_kk, sh_m;
  __shared__ int sh_nlt;
  __shared__ unsigned sh_mcnt;

  const int bid = blockIdx.x;
  const int b = bid >> 10;
  const int tid = threadIdx.x;
  const int lane = tid & 63;
  const int wv = tid >> 6;

  const float4 q = *reinterpret_cast<const float4*>(ws + OFF_QP + (size_t)bid*4);
  const float qx=q.x, qy=q.y, qz=q.z, q2=q.w;
  const float4* pb = reinterpret_cast<const float4*>(ws + OFF_P4) + (size_t)b*NN;

  unsigned k[16];            // static-indexed only (all loops unrolled)
  #pragma unroll
  for (int j=0;j<16;j++){
    int n = tid + j*256;
    float4 P = pb[n];
    float dot = __fadd_rn(__fadd_rn(__fmul_rn(qx,P.x),__fmul_rn(qy,P.y)),__fmul_rn(qz,P.z));
    float d = __fsub_rn(__fadd_rn(q2, P.w), __fmul_rn(2.0f,dot));
    unsigned u = __float_as_uint(d);
    k[j] = u ^ (unsigned)(((int)u>>31) | (int)0x80000000);
  }

  // radix levels from the top byte; stop as soon as boundary-bin count fits
  unsigned maskhi = 0, prefix = 0;
  int kk = KK;
  int Ls = 0;
  unsigned bs = 0;
  for (int L=3; L>=0; --L){
    const int shift = L*8;
    hist[tid] = 0;
    __syncthreads();
    #pragma unroll
    for (int j=0;j<16;j++){
      if ((k[j] & maskhi) == prefix) atomicAdd(&hist[(k[j]>>shift)&0xFFu], 1u);
    }
    __syncthreads();
    unsigned orig = hist[tid];
    unsigned v = orig;
    #pragma unroll
    for (int off=1; off<64; off<<=1){
      unsigned u = __shfl_up(v, (unsigned)off, 64);
      if (lane >= off) v += u;
    }
    if (lane==63) wsum[wv] = v;
    __syncthreads();
    unsigned add = 0;
    #pragma unroll
    for (int kq=0;kq<3;kq++) if (wv > kq) add += wsum[kq];
    unsigned cum = v + add;
    unsigned lower = cum - orig;
    if (cum >= (unsigned)kk && lower < (unsigned)kk){
      sh_b = (unsigned)tid; sh_kk = (unsigned)kk - lower; sh_m = orig;
    }
    __syncthreads();
    unsigned bnow = sh_b; kk = (int)sh_kk;
    unsigned m = sh_m;
    if (m <= CANDCAP || L == 0){ bs = bnow; Ls = L; break; }
    prefix |= bnow << shift;
    maskhi |= 0xFFu << shift;
  }
  const int shf = Ls*8;
  const unsigned M = maskhi | (0xFFu << shf);
  const unsigned T = prefix | (bs << shf);

  if (tid==0){ sh_nlt = 0; sh_mcnt = 0; }
  __syncthreads();
  #pragma unroll
  for (int j=0;j<16;j++){
    unsigned mk = k[j] & M;
    int n = tid + j*256;
    if (mk < T){ int p = atomicAdd(&sh_nlt,1); sel[p] = n; }
    else if (mk == T){
      unsigned p = atomicAdd(&sh_mcnt,1u);
      if (p < CANDCAP) cand[p] = ((unsigned long long)k[j]<<32) | (unsigned)n;
    }
  }
  __syncthreads();
  const int nlt = sh_nlt;                  // == KK - kk
  const unsigned m = (sh_mcnt < CANDCAP) ? sh_mcnt : CANDCAP;
  // exact rank among candidates: (key, idx) lexicographic == packed u64 order
  for (unsigned i=tid; i<m; i+=256){
    const unsigned long long ci = cand[i];
    unsigned r = 0;
    for (unsigned jj=0; jj<m; ++jj) r += (cand[jj] < ci) ? 1u : 0u;
    if (r < (unsigned)kk) sel[nlt + (int)r] = (int)(ci & 0xFFFFFFFFu);
  }
  __syncthreads();

  if (tid < KK){
    int n = sel[tid];
    float4 P = pb[n];
    float v6[6];
    v6[0] = P.x-qx; v6[1] = P.y-qy; v6[2] = P.z-qz;
    const float* pt = pts + ((size_t)b*NN + n)*3;
    v6[3] = pt[0]; v6[4] = pt[1]; v6[5] = pt[2];
    size_t pidx = (size_t)bid*KK + tid;
    float* xg = ws + OFF_XG;
    #pragma unroll
    for (int c=0;c<6;c++) xg[(size_t)c*MPTS + pidx] = v6[c];
    // layer-0 input moments (6 sums + 21 upper-tri products)
    float mm[27];
    int mi = 0;
    #pragma unroll
    for (int c=0;c<6;c++) mm[mi++] = v6[c];
    #pragma unroll
    for (int c=0;c<6;c++){
      #pragma unroll
      for (int c2=c;c2<6;c2++) mm[mi++] = v6[c]*v6[c2];
    }
    #pragma unroll
    for (int off=16; off>=1; off>>=1){
      #pragma unroll
      for (int qq=0;qq<27;qq++) mm[qq] += __shfl_xor(mm[qq], off, 64);
    }
    if (tid==0){
      float* mom = ws + OFF_MOM;
      #pragma unroll
      for (int qq=0;qq<27;qq++) atomicAdd(&mom[qq], mm[qq]);
    }
  }
}

__global__ void finalize0_kernel(const float* __restrict__ w0, const float* __restrict__ b0,
                                 const float* __restrict__ g0, const float* __restrict__ t0,
                                 float* __restrict__ ws)
{
  int o = threadIdx.x; // 64 threads
  const float* mom = ws + OFF_MOM;
  float w[6];
  #pragma unroll
  for (int c=0;c<6;c++) w[c] = w0[o*6+c];
  float bo = b0[o];
  float wS = 0.f;
  #pragma unroll
  for (int c=0;c<6;c++) wS += w[c]*mom[c];
  const float Mf = (float)MPTS;
  float mean = (wS + Mf*bo) / Mf;
  float qsum = 0.f;
  int mi = 6;
  #pragma unroll
  for (int c=0;c<6;c++){
    #pragma unroll
    for (int c2=c;c2<6;c2++){
      float f = (c==c2)?1.f:2.f;
      qsum += f * w[c]*w[c2]*mom[mi];
      mi++;
    }
  }
  float E2  = (qsum + 2.f*bo*wS + Mf*bo*bo) / Mf;
  float var = E2 - mean*mean;
  float sc  = g0[o] / sqrtf(var + EPSF);
  ws[OFF_SC0+o] = sc;
  ws[OFF_SH0+o] = t0[o] - mean*sc;
}

// thread = point: recompute h0 per channel on the fly, accumulate y1 in two
// chunks of 32 (a[32] only live array), store raw y1 as bf16 channel-major.
__global__ __launch_bounds__(256) void l1_kernel(
    const float* __restrict__ w0g, const float* __restrict__ b0g,
    const float* __restrict__ w1g, const float* __restrict__ b1g,
    float* __restrict__ ws)
{
  __shared__ float sw0[64*8];    // w0[c][0..5] at c*8
  __shared__ float sw1T[4096];   // [c][o]
  __shared__ float sb0[64], ssc0[64], ssh0[64], sb1[64];
  const int tid = threadIdx.x;
  for (int i=tid;i<384;i+=256){ int o=i/6, c=i-o*6; sw0[o*8+c] = w0g[i]; }
  // transpose on the global-read side: LDS writes are consecutive (no conflicts)
  for (int i=tid;i<4096;i+=256){ int c=i>>6, o=i&63; sw1T[c*64+o] = w1g[o*64+c]; }
  if (tid<64){ sb0[tid]=b0g[tid]; sb1[tid]=b1g[tid];
               ssc0[tid]=ws[OFF_SC0+tid]; ssh0[tid]=ws[OFF_SH0+tid]; }
  __syncthreads();

  const size_t p = (size_t)blockIdx.x*256 + tid;
  const float* xg = ws + OFF_XG;
  const float x0=xg[p],        x1=xg[MPTS+p],   x2=xg[2ul*MPTS+p];
  const float x3=xg[3ul*MPTS+p], x4=xg[4ul*MPTS+p], x5=xg[5ul*MPTS+p];
  unsigned short* y1 = (unsigned short*)(ws + OFF_Y1U);

  for (int ch=0; ch<2; ++ch){
    float a[32];
    #pragma unroll
    for (int j=0;j<32;j++) a[j] = sb1[ch*32+j];
    for (int c=0;c<64;c++){
      const float4 wa = *reinterpret_cast<const float4*>(&sw0[c*8]);
      const float2 wb = *reinterpret_cast<const float2*>(&sw0[c*8+4]);
      float y = sb0[c];
      y = fmaf(wa.x,x0,y); y = fmaf(wa.y,x1,y); y = fmaf(wa.z,x2,y);
      y = fmaf(wa.w,x3,y); y = fmaf(wb.x,x4,y); y = fmaf(wb.y,x5,y);
      const float h = fmaxf(fmaf(ssc0[c], y, ssh0[c]), 0.f);
      const float4* wr = reinterpret_cast<const float4*>(&sw1T[c*64 + ch*32]);
      #pragma unroll
      for (int qq=0;qq<8;qq++){
        float4 wvv = wr[qq];
        a[qq*4+0] = fmaf(wvv.x,h,a[qq*4+0]);
        a[qq*4+1] = fmaf(wvv.y,h,a[qq*4+1]);
        a[qq*4+2] = fmaf(wvv.z,h,a[qq*4+2]);
        a[qq*4+3] = fmaf(wvv.w,h,a[qq*4+3]);
      }
    }
    #pragma unroll
    for (int j=0;j<32;j++){
      unsigned u = __float_as_uint(a[j]);
      u = (u + 0x7FFFu + ((u>>16)&1u)) >> 16;   // RNE f32->bf16
      y1[(size_t)(ch*32+j)*MPTS + p] = (unsigned short)u;
    }
  }
}

// reduce per-channel sum/sumsq of y1 (bf16): 8 slice-blocks per channel
__global__ __launch_bounds__(256) void stats1_kernel(float* __restrict__ ws)
{
  const int c  = blockIdx.x >> 3;
  const int sl = blockIdx.x & 7;
  const unsigned short* y1 = (const unsigned short*)(ws + OFF_Y1U);
  const uint2* src = (const uint2*)(y1 + (size_t)c*MPTS + (size_t)sl*(MPTS/8));
  float sv=0.f, sq=0.f;
  for (int kq=threadIdx.x; kq<MPTS/32; kq+=256){
    uint2 u = src[kq];
    float v0 = __uint_as_float((u.x & 0xFFFFu)<<16);
    float v1 = __uint_as_float(u.x & 0xFFFF0000u);
    float v2 = __uint_as_float((u.y & 0xFFFFu)<<16);
    float v3 = __uint_as_float(u.y & 0xFFFF0000u);
    sv += (v0+v1)+(v2+v3);
    sq += (v0*v0+v1*v1)+(v2*v2+v3*v3);
  }
  #pragma unroll
  for (int off=32; off>=1; off>>=1){
    sv += __shfl_xor(sv,off,64); sq += __shfl_xor(sq,off,64);
  }
  __shared__ float r[8];
  const int lane = threadIdx.x & 63, wv = threadIdx.x >> 6;
  if (lane==0){ r[wv]=sv; r[4+wv]=sq; }
  __syncthreads();
  if (threadIdx.x==0){
    atomicAdd(&ws[OFF_S1SUM+c], r[0]+r[1]+r[2]+r[3]);
    atomicAdd(&ws[OFF_S1SQ+c],  r[4]+r[5]+r[6]+r[7]);
  }
}

__global__ void finalize1_kernel(const float* __restrict__ g1, const float* __restrict__ t1,
                                 float* __restrict__ ws)
{
  int o = threadIdx.x;
  const float Mf = (float)MPTS;
  float mean = ws[OFF_S1SUM+o]/Mf;
  float var  = ws[OFF_S1SQ+o]/Mf - mean*mean;
  float sc = g1[o]/sqrtf(var+EPSF);
  ws[OFF_SC1+o]=sc; ws[OFF_SH1+o]=t1[o]-mean*sc;
}

// thread = point: h1_c read from global y1 (bf16) on the fly; y2 in 8 chunks
// of 16 channels (a[16] only live array); stats + per-group max/min of raw y2.
__global__ __launch_bounds__(256) void l2_kernel(
    const float* __restrict__ w2g, const float* __restrict__ b2g,
    float* __restrict__ ws)
{
  __shared__ float sw2T[8192];   // [c][o] 64x128
  __shared__ float sb2[128];
  __shared__ float s1c[64], s1h[64];
  __shared__ float red[256];
  const int tid = threadIdx.x;
  for (int i=tid;i<8192;i+=256){ int c=i>>7, o=i&127; sw2T[c*128+o] = w2g[o*64+c]; }
  if (tid<128) sb2[tid]=b2g[tid];
  if (tid<64){ s1c[tid]=ws[OFF_SC1+tid]; s1h[tid]=ws[OFF_SH1+tid]; }
  red[tid]=0.f;
  __syncthreads();

  const size_t p = (size_t)blockIdx.x*256 + tid;
  const unsigned short* y1 = (const unsigned short*)(ws + OFF_Y1U);
  const int lane = tid & 63;
  const int l32  = tid & 31;
  const size_t gidx = p >> 5;
  float* maxb = ws + OFF_MAXB;
  float* minb = ws + OFF_MINB;

  for (int oc=0; oc<8; ++oc){
    float a[16];
    #pragma unroll
    for (int j=0;j<16;j++) a[j] = sb2[oc*16+j];
    for (int c=0;c<64;c++){
      float v = __uint_as_float(((unsigned)y1[(size_t)c*MPTS + p])<<16);
      const float h = fmaxf(fmaf(s1c[c], v, s1h[c]), 0.f);
      const float4* wr = reinterpret_cast<const float4*>(&sw2T[c*128 + oc*16]);
      #pragma unroll
      for (int qq=0;qq<4;qq++){
        float4 wvv = wr[qq];
        a[qq*4+0] = fmaf(wvv.x,h,a[qq*4+0]);
        a[qq*4+1] = fmaf(wvv.y,h,a[qq*4+1]);
        a[qq*4+2] = fmaf(wvv.z,h,a[qq*4+2]);
        a[qq*4+3] = fmaf(wvv.w,h,a[qq*4+3]);
      }
    }
    #pragma unroll
    for (int j=0;j<16;j++){
      const int o = oc*16 + j;
      float sv = a[j], sq = a[j]*a[j];
      #pragma unroll
      for (int off=32; off>=1; off>>=1){
        sv += __shfl_xor(sv,off,64);
        sq += __shfl_xor(sq,off,64);
      }
      if (lane == (o & 63)){
        atomicAdd(&red[o],     sv);
        atomicAdd(&red[128+o], sq);
      }
      float mx = a[j], mn = a[j];
      #pragma unroll
      for (int off=16; off>=1; off>>=1){
        mx = fmaxf(mx, __shfl_xor(mx,off,64));
        mn = fminf(mn, __shfl_xor(mn,off,64));
      }
      if (l32 == (o & 31)){
        maxb[gidx*128 + o] = mx;
        minb[gidx*128 + o] = mn;
      }
    }
  }
  __syncthreads();
  atomicAdd(&ws[OFF_S2SUM + tid], red[tid]);
}

__global__ __launch_bounds__(256) void final_out_kernel(
    const float* __restrict__ g2, const float* __restrict__ t2,
    const float* __restrict__ ws, float* __restrict__ out)
{
  const int g = blockIdx.x*256 + threadIdx.x; // B*S*128 threads
  const int o = g & 127;
  const float Mf = (float)MPTS;
  float mean = ws[OFF_S2SUM+o] / Mf;
  float var  = ws[OFF_S2SQ+o] / Mf - mean*mean;
  float sc = g2[o] / sqrtf(var + EPSF);
  float sh = t2[o] - mean*sc;
  // relu(sc*y+sh) monotone in y: group max if sc>0 else group min
  float v = (sc > 0.f) ? ws[OFF_MAXB+g] : ws[OFF_MINB+g];
  out[BB*SS*3 + g] = fmaxf(fmaf(sc, v, sh), 0.f);
}

extern "C" void kernel_launch(void* const* d_in, const int* in_sizes, int n_in,
                              void* d_out, int out_size, void* d_ws, size_t ws_size,
                              hipStream_t stream)
{
  const float* xyz = (const float*)d_in[0];
  const float* pts = (const float*)d_in[1];
  const int*   fps = (const int*)d_in[2];
  const float* w0  = (const float*)d_in[3];
  const float* b0  = (const float*)d_in[4];
  const float* g0  = (const float*)d_in[5];
  const float* t0  = (const float*)d_in[6];
  const float* w1  = (const float*)d_in[7];
  const float* b1  = (const float*)d_in[8];
  const float* g1  = (const float*)d_in[9];
  const float* t1  = (const float*)d_in[10];
  const float* w2  = (const float*)d_in[11];
  const float* b2  = (const float*)d_in[12];
  const float* g2  = (const float*)d_in[13];
  const float* t2  = (const float*)d_in[14];
  float* out = (float*)d_out;
  float* ws  = (float*)d_ws;

  hipMemsetAsync((void*)(ws + OFF_ST), 0, 512*sizeof(float), stream);
  prep_kernel<<<320,256,0,stream>>>(xyz, fps, out, ws);
  knn_group_kernel<<<BB*SS,256,0,stream>>>(pts, ws);
  finalize0_kernel<<<1,64,0,stream>>>(w0,b0,g0,t0,ws);
  l1_kernel<<<MPTS/256,256,0,stream>>>(w0,b0,w1,b1,ws);
  stats1_kernel<<<512,256,0,stream>>>(ws);
  finalize1_kernel<<<1,64,0,stream>>>(g1,t1,ws);
  l2_kernel<<<MPTS/256,256,0,stream>>>(w2,b2,ws);
  final_out_kernel<<<(BB*SS*128)/256,256,0,stream>>>(g2,t2,ws,out);
}

// Round 7
// 776.222 us; speedup vs baseline: 25.2330x; 5.1820x over previous
//
#include <hip/hip_runtime.h>

#define BB 16
#define NN 4096
#define SS 1024
#define KK 32
#define MPTS (BB*SS*KK)      // 524288
#define EPSF 1e-5f
#define CANDCAP 2048
#define NARROW 512

// workspace layout (float offsets)
#define OFF_QP    0                       // B*S*4
#define OFF_P4    (OFF_QP + BB*SS*4)      // B*N*4
#define OFF_ST    (OFF_P4 + BB*NN*4)      // 512 floats zeroed each call
#define OFF_MOM   (OFF_ST)                // 27
#define OFF_S1SUM (OFF_ST+32)             // 64
#define OFF_S1SQ  (OFF_ST+96)             // 64
#define OFF_S2SUM (OFF_ST+160)            // 128
#define OFF_S2SQ  (OFF_ST+288)            // 128
#define OFF_SC0   (OFF_ST+512)
#define OFF_SH0   (OFF_SC0+64)
#define OFF_SC1   (OFF_SH0+64)
#define OFF_SH1   (OFF_SC1+64)
#define OFF_XG    (OFF_ST+1280)           // 6*MPTS channel-major
#define OFF_MAXB  (OFF_XG + 6*MPTS)       // B*S*128
#define OFF_MINB  (OFF_MAXB + BB*SS*128)  // B*S*128
#define OFF_Y1U   (OFF_MINB + BB*SS*128)  // bf16 (ushort) [64][MPTS] -> 67MB
// knn's per-block moment partials [27][BB*SS] reuse the Y1U region (l1
// overwrites it only after mom_reduce+finalize0 have consumed the partials)
#define OFF_MOMP  (OFF_Y1U)

__global__ __launch_bounds__(256) void prep_kernel(
    const float* __restrict__ xyz, const int* __restrict__ fps,
    float* __restrict__ out, float* __restrict__ ws)
{
  const int g = blockIdx.x*256 + threadIdx.x;
  if (g < BB*NN){
    const float* p = xyz + (size_t)g*3;
    float x=p[0], y=p[1], z=p[2];
    float x2 = __fadd_rn(__fadd_rn(__fmul_rn(x,x),__fmul_rn(y,y)),__fmul_rn(z,z));
    *reinterpret_cast<float4*>(ws + OFF_P4 + (size_t)g*4) = make_float4(x,y,z,x2);
  } else {
    int j = g - BB*NN;
    if (j < BB*SS){
      int b = j >> 10;
      int idx = fps[j];
      const float* p = xyz + ((size_t)b*NN + idx)*3;
      float x=p[0], y=p[1], z=p[2];
      out[(size_t)j*3+0]=x; out[(size_t)j*3+1]=y; out[(size_t)j*3+2]=z;
      float q2 = __fadd_rn(__fadd_rn(__fmul_rn(x,x),__fmul_rn(y,y)),__fmul_rn(z,z));
      *reinterpret_cast<float4*>(ws + OFF_QP + (size_t)j*4) = make_float4(x,y,z,q2);
    }
  }
}

// one block per query: exact 32-NN. Keys in registers; histogram levels
// narrow until boundary-bin count <= NARROW; compact candidates as packed
// (key<<32|idx) u64; exact parallel rank-select. NO global atomics.
__global__ __launch_bounds__(256) void knn_group_kernel(
    const float* __restrict__ pts, float* __restrict__ ws)
{
  __shared__ unsigned hist[256];
  __shared__ unsigned wsum[4];
  __shared__ unsigned long long cand[CANDCAP];
  __shared__ int sel[KK];
  __shared__ unsigned sh_b, sh_kk, sh_m;
  __shared__ int sh_nlt;
  __shared__ unsigned sh_mcnt;

  const int bid = blockIdx.x;
  const int b = bid >> 10;
  const int tid = threadIdx.x;
  const int lane = tid & 63;
  const int wv = tid >> 6;

  const float4 q = *reinterpret_cast<const float4*>(ws + OFF_QP + (size_t)bid*4);
  const float qx=q.x, qy=q.y, qz=q.z, q2=q.w;
  const float4* pb = reinterpret_cast<const float4*>(ws + OFF_P4) + (size_t)b*NN;

  unsigned k[16];            // static-indexed only (all loops unrolled)
  #pragma unroll
  for (int j=0;j<16;j++){
    int n = tid + j*256;
    float4 P = pb[n];
    float dot = __fadd_rn(__fadd_rn(__fmul_rn(qx,P.x),__fmul_rn(qy,P.y)),__fmul_rn(qz,P.z));
    float d = __fsub_rn(__fadd_rn(q2, P.w), __fmul_rn(2.0f,dot));
    unsigned u = __float_as_uint(d);
    k[j] = u ^ (unsigned)(((int)u>>31) | (int)0x80000000);
  }

  const unsigned long long mlt = (lane==0) ? 0ull : (~0ull >> (64-lane));
  unsigned maskhi = 0, prefix = 0;
  int kk = KK;
  int Ls = 3;
  unsigned bs = 0;
  for (int L=3; L>=0; --L){
    const int shift = L*8;
    hist[tid] = 0;
    __syncthreads();
    if (L==3){
      // all keys active: ballot-leader counting (bins are concentrated ->
      // plain per-lane atomics would storm the same LDS address)
      #pragma unroll
      for (int j=0;j<16;j++){
        unsigned bin = k[j]>>24;
        unsigned long long bm = ~0ull;
        #pragma unroll
        for (int bit=0;bit<8;bit++){
          unsigned long long bb = __ballot((int)((bin>>bit)&1u));
          bm &= ((bin>>bit)&1u) ? bb : ~bb;
        }
        if ((bm & mlt) == 0ull) atomicAdd(&hist[bin], (unsigned)__popcll(bm));
      }
    } else {
      // few active keys, spread bins: plain atomics are fine
      #pragma unroll
      for (int j=0;j<16;j++){
        if ((k[j] & maskhi) == prefix) atomicAdd(&hist[(k[j]>>shift)&0xFFu], 1u);
      }
    }
    __syncthreads();
    unsigned orig = hist[tid];
    unsigned v = orig;
    #pragma unroll
    for (int off=1; off<64; off<<=1){
      unsigned u = __shfl_up(v, (unsigned)off, 64);
      if (lane >= off) v += u;
    }
    if (lane==63) wsum[wv] = v;
    __syncthreads();
    unsigned add = 0;
    #pragma unroll
    for (int kq=0;kq<3;kq++) if (wv > kq) add += wsum[kq];
    unsigned cum = v + add;
    unsigned lower = cum - orig;
    if (cum >= (unsigned)kk && lower < (unsigned)kk){
      sh_b = (unsigned)tid; sh_kk = (unsigned)kk - lower; sh_m = orig;
    }
    __syncthreads();
    unsigned bnow = sh_b; kk = (int)sh_kk;
    unsigned m = sh_m;
    if (m <= NARROW || L == 0){ bs = bnow; Ls = L; break; }
    prefix |= bnow << shift;
    maskhi |= 0xFFu << shift;
  }
  const int shf = Ls*8;
  const unsigned M = maskhi | (0xFFu << shf);
  const unsigned T = prefix | (bs << shf);

  if (tid==0){ sh_nlt = 0; sh_mcnt = 0; }
  __syncthreads();
  #pragma unroll
  for (int j=0;j<16;j++){
    unsigned mk = k[j] & M;
    int n = tid + j*256;
    if (mk < T){ int p = atomicAdd(&sh_nlt,1); sel[p] = n; }
    else if (mk == T){
      unsigned p = atomicAdd(&sh_mcnt,1u);
      if (p < CANDCAP) cand[p] = ((unsigned long long)k[j]<<32) | (unsigned)n;
    }
  }
  __syncthreads();
  const int nlt = sh_nlt;                  // == KK - kk
  const unsigned m = (sh_mcnt < CANDCAP) ? sh_mcnt : CANDCAP;
  // exact rank among candidates: (key, idx) lexicographic == packed u64 order
  for (unsigned i=tid; i<m; i+=256){
    const unsigned long long ci = cand[i];
    unsigned r = 0;
    #pragma unroll 4
    for (unsigned jj=0; jj<m; ++jj) r += (cand[jj] < ci) ? 1u : 0u;
    if (r < (unsigned)kk) sel[nlt + (int)r] = (int)(ci & 0xFFFFFFFFu);
  }
  __syncthreads();

  if (tid < KK){
    int n = sel[tid];
    float4 P = pb[n];
    float v6[6];
    v6[0] = P.x-qx; v6[1] = P.y-qy; v6[2] = P.z-qz;
    const float* pt = pts + ((size_t)b*NN + n)*3;
    v6[3] = pt[0]; v6[4] = pt[1]; v6[5] = pt[2];
    size_t pidx = (size_t)bid*KK + tid;
    float* xg = ws + OFF_XG;
    #pragma unroll
    for (int c=0;c<6;c++) xg[(size_t)c*MPTS + pidx] = v6[c];
    // layer-0 input moments (6 sums + 21 upper-tri products)
    float mm[27];
    int mi = 0;
    #pragma unroll
    for (int c=0;c<6;c++) mm[mi++] = v6[c];
    #pragma unroll
    for (int c=0;c<6;c++){
      #pragma unroll
      for (int c2=c;c2<6;c2++) mm[mi++] = v6[c]*v6[c2];
    }
    #pragma unroll
    for (int off=16; off>=1; off>>=1){
      #pragma unroll
      for (int qq=0;qq<27;qq++) mm[qq] += __shfl_xor(mm[qq], off, 64);
    }
    if (tid==0){
      // per-block partials, PLAIN stores (global same-address atomics from
      // 16384 blocks were the 3.4ms serialization)
      float* momp = ws + OFF_MOMP;
      #pragma unroll
      for (int qq=0;qq<27;qq++) momp[(size_t)qq*(BB*SS) + bid] = mm[qq];
    }
  }
}

// sum the [27][16384] partials -> OFF_MOM
__global__ __launch_bounds__(256) void mom_reduce_kernel(float* __restrict__ ws)
{
  const int q = blockIdx.x;
  const float* src = ws + OFF_MOMP + (size_t)q*(BB*SS);
  float s = 0.f;
  for (int i=threadIdx.x; i<BB*SS; i+=256) s += src[i];
  #pragma unroll
  for (int off=32; off>=1; off>>=1) s += __shfl_xor(s,off,64);
  __shared__ float r[4];
  const int lane = threadIdx.x & 63, wv = threadIdx.x >> 6;
  if (lane==0) r[wv]=s;
  __syncthreads();
  if (threadIdx.x==0) ws[OFF_MOM+q] = r[0]+r[1]+r[2]+r[3];
}

__global__ void finalize0_kernel(const float* __restrict__ w0, const float* __restrict__ b0,
                                 const float* __restrict__ g0, const float* __restrict__ t0,
                                 float* __restrict__ ws)
{
  int o = threadIdx.x; // 64 threads
  const float* mom = ws + OFF_MOM;
  float w[6];
  #pragma unroll
  for (int c=0;c<6;c++) w[c] = w0[o*6+c];
  float bo = b0[o];
  float wS = 0.f;
  #pragma unroll
  for (int c=0;c<6;c++) wS += w[c]*mom[c];
  const float Mf = (float)MPTS;
  float mean = (wS + Mf*bo) / Mf;
  float qsum = 0.f;
  int mi = 6;
  #pragma unroll
  for (int c=0;c<6;c++){
    #pragma unroll
    for (int c2=c;c2<6;c2++){
      float f = (c==c2)?1.f:2.f;
      qsum += f * w[c]*w[c2]*mom[mi];
      mi++;
    }
  }
  float E2  = (qsum + 2.f*bo*wS + Mf*bo*bo) / Mf;
  float var = E2 - mean*mean;
  float sc  = g0[o] / sqrtf(var + EPSF);
  ws[OFF_SC0+o] = sc;
  ws[OFF_SH0+o] = t0[o] - mean*sc;
}

// thread = point: recompute h0 per channel on the fly, accumulate y1 in two
// chunks of 32 (a[32] only live array), store raw y1 as bf16 channel-major.
__global__ __launch_bounds__(256) void l1_kernel(
    const float* __restrict__ w0g, const float* __restrict__ b0g,
    const float* __restrict__ w1g, const float* __restrict__ b1g,
    float* __restrict__ ws)
{
  __shared__ float sw0[64*8];    // w0[c][0..5] at c*8
  __shared__ float sw1T[4096];   // [c][o]
  __shared__ float sb0[64], ssc0[64], ssh0[64], sb1[64];
  const int tid = threadIdx.x;
  for (int i=tid;i<384;i+=256){ int o=i/6, c=i-o*6; sw0[o*8+c] = w0g[i]; }
  // transpose on the global-read side: LDS writes are consecutive (no conflicts)
  for (int i=tid;i<4096;i+=256){ int c=i>>6, o=i&63; sw1T[c*64+o] = w1g[o*64+c]; }
  if (tid<64){ sb0[tid]=b0g[tid]; sb1[tid]=b1g[tid];
               ssc0[tid]=ws[OFF_SC0+tid]; ssh0[tid]=ws[OFF_SH0+tid]; }
  __syncthreads();

  const size_t p = (size_t)blockIdx.x*256 + tid;
  const float* xg = ws + OFF_XG;
  const float x0=xg[p],        x1=xg[MPTS+p],   x2=xg[2ul*MPTS+p];
  const float x3=xg[3ul*MPTS+p], x4=xg[4ul*MPTS+p], x5=xg[5ul*MPTS+p];
  unsigned short* y1 = (unsigned short*)(ws + OFF_Y1U);

  for (int ch=0; ch<2; ++ch){
    float a[32];
    #pragma unroll
    for (int j=0;j<32;j++) a[j] = sb1[ch*32+j];
    for (int c=0;c<64;c++){
      const float4 wa = *reinterpret_cast<const float4*>(&sw0[c*8]);
      const float2 wb = *reinterpret_cast<const float2*>(&sw0[c*8+4]);
      float y = sb0[c];
      y = fmaf(wa.x,x0,y); y = fmaf(wa.y,x1,y); y = fmaf(wa.z,x2,y);
      y = fmaf(wa.w,x3,y); y = fmaf(wb.x,x4,y); y = fmaf(wb.y,x5,y);
      const float h = fmaxf(fmaf(ssc0[c], y, ssh0[c]), 0.f);
      const float4* wr = reinterpret_cast<const float4*>(&sw1T[c*64 + ch*32]);
      #pragma unroll
      for (int qq=0;qq<8;qq++){
        float4 wvv = wr[qq];
        a[qq*4+0] = fmaf(wvv.x,h,a[qq*4+0]);
        a[qq*4+1] = fmaf(wvv.y,h,a[qq*4+1]);
        a[qq*4+2] = fmaf(wvv.z,h,a[qq*4+2]);
        a[qq*4+3] = fmaf(wvv.w,h,a[qq*4+3]);
      }
    }
    #pragma unroll
    for (int j=0;j<32;j++){
      unsigned u = __float_as_uint(a[j]);
      u = (u + 0x7FFFu + ((u>>16)&1u)) >> 16;   // RNE f32->bf16
      y1[(size_t)(ch*32+j)*MPTS + p] = (unsigned short)u;
    }
  }
}

// reduce per-channel sum/sumsq of y1 (bf16): 8 slice-blocks per channel
__global__ __launch_bounds__(256) void stats1_kernel(float* __restrict__ ws)
{
  const int c  = blockIdx.x >> 3;
  const int sl = blockIdx.x & 7;
  const unsigned short* y1 = (const unsigned short*)(ws + OFF_Y1U);
  const uint2* src = (const uint2*)(y1 + (size_t)c*MPTS + (size_t)sl*(MPTS/8));
  float sv=0.f, sq=0.f;
  for (int kq=threadIdx.x; kq<MPTS/32; kq+=256){
    uint2 u = src[kq];
    float v0 = __uint_as_float((u.x & 0xFFFFu)<<16);
    float v1 = __uint_as_float(u.x & 0xFFFF0000u);
    float v2 = __uint_as_float((u.y & 0xFFFFu)<<16);
    float v3 = __uint_as_float(u.y & 0xFFFF0000u);
    sv += (v0+v1)+(v2+v3);
    sq += (v0*v0+v1*v1)+(v2*v2+v3*v3);
  }
  #pragma unroll
  for (int off=32; off>=1; off>>=1){
    sv += __shfl_xor(sv,off,64); sq += __shfl_xor(sq,off,64);
  }
  __shared__ float r[8];
  const int lane = threadIdx.x & 63, wv = threadIdx.x >> 6;
  if (lane==0){ r[wv]=sv; r[4+wv]=sq; }
  __syncthreads();
  if (threadIdx.x==0){
    atomicAdd(&ws[OFF_S1SUM+c], r[0]+r[1]+r[2]+r[3]);
    atomicAdd(&ws[OFF_S1SQ+c],  r[4]+r[5]+r[6]+r[7]);
  }
}

__global__ void finalize1_kernel(const float* __restrict__ g1, const float* __restrict__ t1,
                                 float* __restrict__ ws)
{
  int o = threadIdx.x;
  const float Mf = (float)MPTS;
  float mean = ws[OFF_S1SUM+o]/Mf;
  float var  = ws[OFF_S1SQ+o]/Mf - mean*mean;
  float sc = g1[o]/sqrtf(var+EPSF);
  ws[OFF_SC1+o]=sc; ws[OFF_SH1+o]=t1[o]-mean*sc;
}

// thread = point: h1_c read from global y1 (bf16) on the fly; y2 in 8 chunks
// of 16 channels (a[16] only live array); stats + per-group max/min of raw y2.
__global__ __launch_bounds__(256) void l2_kernel(
    const float* __restrict__ w2g, const float* __restrict__ b2g,
    float* __restrict__ ws)
{
  __shared__ float sw2T[8192];   // [c][o] 64x128
  __shared__ float sb2[128];
  __shared__ float s1c[64], s1h[64];
  __shared__ float red[256];
  const int tid = threadIdx.x;
  for (int i=tid;i<8192;i+=256){ int c=i>>7, o=i&127; sw2T[c*128+o] = w2g[o*64+c]; }
  if (tid<128) sb2[tid]=b2g[tid];
  if (tid<64){ s1c[tid]=ws[OFF_SC1+tid]; s1h[tid]=ws[OFF_SH1+tid]; }
  red[tid]=0.f;
  __syncthreads();

  const size_t p = (size_t)blockIdx.x*256 + tid;
  const unsigned short* y1 = (const unsigned short*)(ws + OFF_Y1U);
  const int lane = tid & 63;
  const int l32  = tid & 31;
  const size_t gidx = p >> 5;
  float* maxb = ws + OFF_MAXB;
  float* minb = ws + OFF_MINB;

  for (int oc=0; oc<8; ++oc){
    float a[16];
    #pragma unroll
    for (int j=0;j<16;j++) a[j] = sb2[oc*16+j];
    for (int c=0;c<64;c++){
      float v = __uint_as_float(((unsigned)y1[(size_t)c*MPTS + p])<<16);
      const float h = fmaxf(fmaf(s1c[c], v, s1h[c]), 0.f);
      const float4* wr = reinterpret_cast<const float4*>(&sw2T[c*128 + oc*16]);
      #pragma unroll
      for (int qq=0;qq<4;qq++){
        float4 wvv = wr[qq];
        a[qq*4+0] = fmaf(wvv.x,h,a[qq*4+0]);
        a[qq*4+1] = fmaf(wvv.y,h,a[qq*4+1]);
        a[qq*4+2] = fmaf(wvv.z,h,a[qq*4+2]);
        a[qq*4+3] = fmaf(wvv.w,h,a[qq*4+3]);
      }
    }
    #pragma unroll
    for (int j=0;j<16;j++){
      const int o = oc*16 + j;
      float sv = a[j], sq = a[j]*a[j];
      #pragma unroll
      for (int off=32; off>=1; off>>=1){
        sv += __shfl_xor(sv,off,64);
        sq += __shfl_xor(sq,off,64);
      }
      if (lane == (o & 63)){
        atomicAdd(&red[o],     sv);
        atomicAdd(&red[128+o], sq);
      }
      float mx = a[j], mn = a[j];
      #pragma unroll
      for (int off=16; off>=1; off>>=1){
        mx = fmaxf(mx, __shfl_xor(mx,off,64));
        mn = fminf(mn, __shfl_xor(mn,off,64));
      }
      if (l32 == (o & 31)){
        maxb[gidx*128 + o] = mx;
        minb[gidx*128 + o] = mn;
      }
    }
  }
  __syncthreads();
  atomicAdd(&ws[OFF_S2SUM + tid], red[tid]);
}

__global__ __launch_bounds__(256) void final_out_kernel(
    const float* __restrict__ g2, const float* __restrict__ t2,
    const float* __restrict__ ws, float* __restrict__ out)
{
  const int g = blockIdx.x*256 + threadIdx.x; // B*S*128 threads
  const int o = g & 127;
  const float Mf = (float)MPTS;
  float mean = ws[OFF_S2SUM+o] / Mf;
  float var  = ws[OFF_S2SQ+o] / Mf - mean*mean;
  float sc = g2[o] / sqrtf(var + EPSF);
  float sh = t2[o] - mean*sc;
  // relu(sc*y+sh) monotone in y: group max if sc>0 else group min
  float v = (sc > 0.f) ? ws[OFF_MAXB+g] : ws[OFF_MINB+g];
  out[BB*SS*3 + g] = fmaxf(fmaf(sc, v, sh), 0.f);
}

extern "C" void kernel_launch(void* const* d_in, const int* in_sizes, int n_in,
                              void* d_out, int out_size, void* d_ws, size_t ws_size,
                              hipStream_t stream)
{
  const float* xyz = (const float*)d_in[0];
  const float* pts = (const float*)d_in[1];
  const int*   fps = (const int*)d_in[2];
  const float* w0  = (const float*)d_in[3];
  const float* b0  = (const float*)d_in[4];
  const float* g0  = (const float*)d_in[5];
  const float* t0  = (const float*)d_in[6];
  const float* w1  = (const float*)d_in[7];
  const float* b1  = (const float*)d_in[8];
  const float* g1  = (const float*)d_in[9];
  const float* t1  = (const float*)d_in[10];
  const float* w2  = (const float*)d_in[11];
  const float* b2  = (const float*)d_in[12];
  const float* g2  = (const float*)d_in[13];
  const float* t2  = (const float*)d_in[14];
  float* out = (float*)d_out;
  float* ws  = (float*)d_ws;

  hipMemsetAsync((void*)(ws + OFF_ST), 0, 512*sizeof(float), stream);
  prep_kernel<<<320,256,0,stream>>>(xyz, fps, out, ws);
  knn_group_kernel<<<BB*SS,256,0,stream>>>(pts, ws);
  mom_reduce_kernel<<<27,256,0,stream>>>(ws);
  finalize0_kernel<<<1,64,0,stream>>>(w0,b0,g0,t0,ws);
  l1_kernel<<<MPTS/256,256,0,stream>>>(w0,b0,w1,b1,ws);
  stats1_kernel<<<512,256,0,stream>>>(ws);
  finalize1_kernel<<<1,64,0,stream>>>(g1,t1,ws);
  l2_kernel<<<MPTS/256,256,0,stream>>>(w2,b2,ws);
  final_out_kernel<<<(BB*SS*128)/256,256,0,stream>>>(g2,t2,ws,out);
}

// Round 8
// 445.508 us; speedup vs baseline: 43.9642x; 1.7423x over previous
//
#include <hip/hip_runtime.h>

#define BB 16
#define NN 4096
#define SS 1024
#define KK 32
#define MPTS (BB*SS*KK)      // 524288
#define EPSF 1e-5f
#define CANDCAP 2048
#define NARROW 512

// workspace layout (float offsets)
#define OFF_QP    0                       // B*S*4
#define OFF_P4    (OFF_QP + BB*SS*4)      // B*N*4
#define OFF_ST    (OFF_P4 + BB*NN*4)      // 512 floats zeroed each call
#define OFF_MOM   (OFF_ST)                // 27
#define OFF_S1SUM (OFF_ST+32)             // 64
#define OFF_S1SQ  (OFF_ST+96)             // 64
#define OFF_S2SUM (OFF_ST+160)            // 128
#define OFF_S2SQ  (OFF_ST+288)            // 128
#define OFF_SC0   (OFF_ST+512)
#define OFF_SH0   (OFF_SC0+64)
#define OFF_SC1   (OFF_SH0+64)
#define OFF_SH1   (OFF_SC1+64)
#define OFF_XG    (OFF_ST+1280)           // 6*MPTS channel-major
#define OFF_MAXB  (OFF_XG + 6*MPTS)       // B*S*128
#define OFF_MINB  (OFF_MAXB + BB*SS*128)  // B*S*128
#define OFF_Y1U   (OFF_MINB + BB*SS*128)  // bf16 (ushort) POINT-major [MPTS][64]
// knn's per-block moment partials [27][BB*SS] reuse the Y1U region (l1
// overwrites it only after mom_reduce+finalize0 have consumed the partials)
#define OFF_MOMP  (OFF_Y1U)

typedef __bf16 bf16x8 __attribute__((ext_vector_type(8)));
typedef float f32x4 __attribute__((ext_vector_type(4)));
typedef unsigned int uintx4 __attribute__((ext_vector_type(4)));

__device__ __forceinline__ unsigned rne_bf16(float f){
  unsigned u = __float_as_uint(f);
  return (u + 0x7FFFu + ((u>>16)&1u)) >> 16;   // RNE f32->bf16 (finite, non-NaN)
}

__global__ __launch_bounds__(256) void prep_kernel(
    const float* __restrict__ xyz, const int* __restrict__ fps,
    float* __restrict__ out, float* __restrict__ ws)
{
  const int g = blockIdx.x*256 + threadIdx.x;
  if (g < BB*NN){
    const float* p = xyz + (size_t)g*3;
    float x=p[0], y=p[1], z=p[2];
    float x2 = __fadd_rn(__fadd_rn(__fmul_rn(x,x),__fmul_rn(y,y)),__fmul_rn(z,z));
    *reinterpret_cast<float4*>(ws + OFF_P4 + (size_t)g*4) = make_float4(x,y,z,x2);
  } else {
    int j = g - BB*NN;
    if (j < BB*SS){
      int b = j >> 10;
      int idx = fps[j];
      const float* p = xyz + ((size_t)b*NN + idx)*3;
      float x=p[0], y=p[1], z=p[2];
      out[(size_t)j*3+0]=x; out[(size_t)j*3+1]=y; out[(size_t)j*3+2]=z;
      float q2 = __fadd_rn(__fadd_rn(__fmul_rn(x,x),__fmul_rn(y,y)),__fmul_rn(z,z));
      *reinterpret_cast<float4*>(ws + OFF_QP + (size_t)j*4) = make_float4(x,y,z,q2);
    }
  }
}

// one block per query: exact 32-NN. Keys in registers; histogram levels
// narrow until boundary-bin count <= NARROW; compact candidates as packed
// (key<<32|idx) u64; exact parallel rank-select. NO global atomics.
__global__ __launch_bounds__(256) void knn_group_kernel(
    const float* __restrict__ pts, float* __restrict__ ws)
{
  __shared__ unsigned hist[256];
  __shared__ unsigned wsum[4];
  __shared__ unsigned long long cand[CANDCAP];
  __shared__ int sel[KK];
  __shared__ unsigned sh_b, sh_kk, sh_m;
  __shared__ int sh_nlt;
  __shared__ unsigned sh_mcnt;

  const int bid = blockIdx.x;
  const int b = bid >> 10;
  const int tid = threadIdx.x;
  const int lane = tid & 63;
  const int wv = tid >> 6;

  const float4 q = *reinterpret_cast<const float4*>(ws + OFF_QP + (size_t)bid*4);
  const float qx=q.x, qy=q.y, qz=q.z, q2=q.w;
  const float4* pb = reinterpret_cast<const float4*>(ws + OFF_P4) + (size_t)b*NN;

  unsigned k[16];            // static-indexed only (all loops unrolled)
  #pragma unroll
  for (int j=0;j<16;j++){
    int n = tid + j*256;
    float4 P = pb[n];
    float dot = __fadd_rn(__fadd_rn(__fmul_rn(qx,P.x),__fmul_rn(qy,P.y)),__fmul_rn(qz,P.z));
    float d = __fsub_rn(__fadd_rn(q2, P.w), __fmul_rn(2.0f,dot));
    unsigned u = __float_as_uint(d);
    k[j] = u ^ (unsigned)(((int)u>>31) | (int)0x80000000);
  }

  const unsigned long long mlt = (lane==0) ? 0ull : (~0ull >> (64-lane));
  unsigned maskhi = 0, prefix = 0;
  int kk = KK;
  int Ls = 3;
  unsigned bs = 0;
  for (int L=3; L>=0; --L){
    const int shift = L*8;
    hist[tid] = 0;
    __syncthreads();
    if (L==3){
      #pragma unroll
      for (int j=0;j<16;j++){
        unsigned bin = k[j]>>24;
        unsigned long long bm = ~0ull;
        #pragma unroll
        for (int bit=0;bit<8;bit++){
          unsigned long long bb = __ballot((int)((bin>>bit)&1u));
          bm &= ((bin>>bit)&1u) ? bb : ~bb;
        }
        if ((bm & mlt) == 0ull) atomicAdd(&hist[bin], (unsigned)__popcll(bm));
      }
    } else {
      #pragma unroll
      for (int j=0;j<16;j++){
        if ((k[j] & maskhi) == prefix) atomicAdd(&hist[(k[j]>>shift)&0xFFu], 1u);
      }
    }
    __syncthreads();
    unsigned orig = hist[tid];
    unsigned v = orig;
    #pragma unroll
    for (int off=1; off<64; off<<=1){
      unsigned u = __shfl_up(v, (unsigned)off, 64);
      if (lane >= off) v += u;
    }
    if (lane==63) wsum[wv] = v;
    __syncthreads();
    unsigned add = 0;
    #pragma unroll
    for (int kq=0;kq<3;kq++) if (wv > kq) add += wsum[kq];
    unsigned cum = v + add;
    unsigned lower = cum - orig;
    if (cum >= (unsigned)kk && lower < (unsigned)kk){
      sh_b = (unsigned)tid; sh_kk = (unsigned)kk - lower; sh_m = orig;
    }
    __syncthreads();
    unsigned bnow = sh_b; kk = (int)sh_kk;
    unsigned m = sh_m;
    if (m <= NARROW || L == 0){ bs = bnow; Ls = L; break; }
    prefix |= bnow << shift;
    maskhi |= 0xFFu << shift;
  }
  const int shf = Ls*8;
  const unsigned M = maskhi | (0xFFu << shf);
  const unsigned T = prefix | (bs << shf);

  if (tid==0){ sh_nlt = 0; sh_mcnt = 0; }
  __syncthreads();
  #pragma unroll
  for (int j=0;j<16;j++){
    unsigned mk = k[j] & M;
    int n = tid + j*256;
    if (mk < T){ int p = atomicAdd(&sh_nlt,1); sel[p] = n; }
    else if (mk == T){
      unsigned p = atomicAdd(&sh_mcnt,1u);
      if (p < CANDCAP) cand[p] = ((unsigned long long)k[j]<<32) | (unsigned)n;
    }
  }
  __syncthreads();
  const int nlt = sh_nlt;                  // == KK - kk
  const unsigned m = (sh_mcnt < CANDCAP) ? sh_mcnt : CANDCAP;
  for (unsigned i=tid; i<m; i+=256){
    const unsigned long long ci = cand[i];
    unsigned r = 0;
    #pragma unroll 4
    for (unsigned jj=0; jj<m; ++jj) r += (cand[jj] < ci) ? 1u : 0u;
    if (r < (unsigned)kk) sel[nlt + (int)r] = (int)(ci & 0xFFFFFFFFu);
  }
  __syncthreads();

  if (tid < KK){
    int n = sel[tid];
    float4 P = pb[n];
    float v6[6];
    v6[0] = P.x-qx; v6[1] = P.y-qy; v6[2] = P.z-qz;
    const float* pt = pts + ((size_t)b*NN + n)*3;
    v6[3] = pt[0]; v6[4] = pt[1]; v6[5] = pt[2];
    size_t pidx = (size_t)bid*KK + tid;
    float* xg = ws + OFF_XG;
    #pragma unroll
    for (int c=0;c<6;c++) xg[(size_t)c*MPTS + pidx] = v6[c];
    float mm[27];
    int mi = 0;
    #pragma unroll
    for (int c=0;c<6;c++) mm[mi++] = v6[c];
    #pragma unroll
    for (int c=0;c<6;c++){
      #pragma unroll
      for (int c2=c;c2<6;c2++) mm[mi++] = v6[c]*v6[c2];
    }
    #pragma unroll
    for (int off=16; off>=1; off>>=1){
      #pragma unroll
      for (int qq=0;qq<27;qq++) mm[qq] += __shfl_xor(mm[qq], off, 64);
    }
    if (tid==0){
      float* momp = ws + OFF_MOMP;
      #pragma unroll
      for (int qq=0;qq<27;qq++) momp[(size_t)qq*(BB*SS) + bid] = mm[qq];
    }
  }
}

// sum the [27][16384] partials -> OFF_MOM
__global__ __launch_bounds__(256) void mom_reduce_kernel(float* __restrict__ ws)
{
  const int q = blockIdx.x;
  const float* src = ws + OFF_MOMP + (size_t)q*(BB*SS);
  float s = 0.f;
  for (int i=threadIdx.x; i<BB*SS; i+=256) s += src[i];
  #pragma unroll
  for (int off=32; off>=1; off>>=1) s += __shfl_xor(s,off,64);
  __shared__ float r[4];
  const int lane = threadIdx.x & 63, wv = threadIdx.x >> 6;
  if (lane==0) r[wv]=s;
  __syncthreads();
  if (threadIdx.x==0) ws[OFF_MOM+q] = r[0]+r[1]+r[2]+r[3];
}

__global__ void finalize0_kernel(const float* __restrict__ w0, const float* __restrict__ b0,
                                 const float* __restrict__ g0, const float* __restrict__ t0,
                                 float* __restrict__ ws)
{
  int o = threadIdx.x; // 64 threads
  const float* mom = ws + OFF_MOM;
  float w[6];
  #pragma unroll
  for (int c=0;c<6;c++) w[c] = w0[o*6+c];
  float bo = b0[o];
  float wS = 0.f;
  #pragma unroll
  for (int c=0;c<6;c++) wS += w[c]*mom[c];
  const float Mf = (float)MPTS;
  float mean = (wS + Mf*bo) / Mf;
  float qsum = 0.f;
  int mi = 6;
  #pragma unroll
  for (int c=0;c<6;c++){
    #pragma unroll
    for (int c2=c;c2<6;c2++){
      float f = (c==c2)?1.f:2.f;
      qsum += f * w[c]*w[c2]*mom[mi];
      mi++;
    }
  }
  float E2  = (qsum + 2.f*bo*wS + Mf*bo*bo) / Mf;
  float var = E2 - mean*mean;
  float sc  = g0[o] / sqrtf(var + EPSF);
  ws[OFF_SC0+o] = sc;
  ws[OFF_SH0+o] = t0[o] - mean*sc;
}

// thread = point: recompute h0 per channel on the fly, accumulate y1 in two
// chunks of 32, store raw y1 as bf16 POINT-major [p][64].
__global__ __launch_bounds__(256) void l1_kernel(
    const float* __restrict__ w0g, const float* __restrict__ b0g,
    const float* __restrict__ w1g, const float* __restrict__ b1g,
    float* __restrict__ ws)
{
  __shared__ float sw0[64*8];    // w0[c][0..5] at c*8
  __shared__ float sw1T[4096];   // [c][o]
  __shared__ float sb0[64], ssc0[64], ssh0[64], sb1[64];
  const int tid = threadIdx.x;
  for (int i=tid;i<384;i+=256){ int o=i/6, c=i-o*6; sw0[o*8+c] = w0g[i]; }
  for (int i=tid;i<4096;i+=256){ int c=i>>6, o=i&63; sw1T[c*64+o] = w1g[o*64+c]; }
  if (tid<64){ sb0[tid]=b0g[tid]; sb1[tid]=b1g[tid];
               ssc0[tid]=ws[OFF_SC0+tid]; ssh0[tid]=ws[OFF_SH0+tid]; }
  __syncthreads();

  const size_t p = (size_t)blockIdx.x*256 + tid;
  const float* xg = ws + OFF_XG;
  const float x0=xg[p],        x1=xg[MPTS+p],   x2=xg[2ul*MPTS+p];
  const float x3=xg[3ul*MPTS+p], x4=xg[4ul*MPTS+p], x5=xg[5ul*MPTS+p];
  unsigned short* y1 = (unsigned short*)(ws + OFF_Y1U);

  for (int ch=0; ch<2; ++ch){
    float a[32];
    #pragma unroll
    for (int j=0;j<32;j++) a[j] = sb1[ch*32+j];
    for (int c=0;c<64;c++){
      const float4 wa = *reinterpret_cast<const float4*>(&sw0[c*8]);
      const float2 wb = *reinterpret_cast<const float2*>(&sw0[c*8+4]);
      float y = sb0[c];
      y = fmaf(wa.x,x0,y); y = fmaf(wa.y,x1,y); y = fmaf(wa.z,x2,y);
      y = fmaf(wa.w,x3,y); y = fmaf(wb.x,x4,y); y = fmaf(wb.y,x5,y);
      const float h = fmaxf(fmaf(ssc0[c], y, ssh0[c]), 0.f);
      const float4* wr = reinterpret_cast<const float4*>(&sw1T[c*64 + ch*32]);
      #pragma unroll
      for (int qq=0;qq<8;qq++){
        float4 wvv = wr[qq];
        a[qq*4+0] = fmaf(wvv.x,h,a[qq*4+0]);
        a[qq*4+1] = fmaf(wvv.y,h,a[qq*4+1]);
        a[qq*4+2] = fmaf(wvv.z,h,a[qq*4+2]);
        a[qq*4+3] = fmaf(wvv.w,h,a[qq*4+3]);
      }
    }
    unsigned uu[16];
    #pragma unroll
    for (int j=0;j<16;j++)
      uu[j] = rne_bf16(a[2*j]) | (rne_bf16(a[2*j+1])<<16);
    uint4* dst = reinterpret_cast<uint4*>(y1 + p*64 + ch*32);
    #pragma unroll
    for (int qq=0;qq<4;qq++)
      dst[qq] = make_uint4(uu[qq*4+0],uu[qq*4+1],uu[qq*4+2],uu[qq*4+3]);
  }
}

// per-channel sum/sumsq of y1 (bf16, point-major)
__global__ __launch_bounds__(256) void stats1_kernel(float* __restrict__ ws)
{
  __shared__ float redS[64], redQ[64];
  const int tid = threadIdx.x;
  if (tid<64){ redS[tid]=0.f; redQ[tid]=0.f; }
  __syncthreads();
  const int lane = tid & 63;
  const int c0 = (lane & 15)*4;     // channels c0..c0+3
  const int prow = tid >> 4;        // 0..15
  const unsigned short* y1 = (const unsigned short*)(ws + OFF_Y1U);
  const int base = blockIdx.x * 2048;
  float sv0=0,sv1=0,sv2=0,sv3=0, sq0=0,sq1=0,sq2=0,sq3=0;
  for (int p = base + prow; p < base + 2048; p += 16){
    uint2 u = *reinterpret_cast<const uint2*>(y1 + (size_t)p*64 + c0);
    float v0 = __uint_as_float(u.x<<16);
    float v1 = __uint_as_float(u.x & 0xFFFF0000u);
    float v2 = __uint_as_float(u.y<<16);
    float v3 = __uint_as_float(u.y & 0xFFFF0000u);
    sv0+=v0; sv1+=v1; sv2+=v2; sv3+=v3;
    sq0=fmaf(v0,v0,sq0); sq1=fmaf(v1,v1,sq1); sq2=fmaf(v2,v2,sq2); sq3=fmaf(v3,v3,sq3);
  }
  sv0 += __shfl_xor(sv0,16,64); sv0 += __shfl_xor(sv0,32,64);
  sv1 += __shfl_xor(sv1,16,64); sv1 += __shfl_xor(sv1,32,64);
  sv2 += __shfl_xor(sv2,16,64); sv2 += __shfl_xor(sv2,32,64);
  sv3 += __shfl_xor(sv3,16,64); sv3 += __shfl_xor(sv3,32,64);
  sq0 += __shfl_xor(sq0,16,64); sq0 += __shfl_xor(sq0,32,64);
  sq1 += __shfl_xor(sq1,16,64); sq1 += __shfl_xor(sq1,32,64);
  sq2 += __shfl_xor(sq2,16,64); sq2 += __shfl_xor(sq2,32,64);
  sq3 += __shfl_xor(sq3,16,64); sq3 += __shfl_xor(sq3,32,64);
  if (lane < 16){
    atomicAdd(&redS[c0+0], sv0); atomicAdd(&redS[c0+1], sv1);
    atomicAdd(&redS[c0+2], sv2); atomicAdd(&redS[c0+3], sv3);
    atomicAdd(&redQ[c0+0], sq0); atomicAdd(&redQ[c0+1], sq1);
    atomicAdd(&redQ[c0+2], sq2); atomicAdd(&redQ[c0+3], sq3);
  }
  __syncthreads();
  if (tid < 64){
    atomicAdd(&ws[OFF_S1SUM+tid], redS[tid]);
    atomicAdd(&ws[OFF_S1SQ+tid],  redQ[tid]);
  }
}

__global__ void finalize1_kernel(const float* __restrict__ g1, const float* __restrict__ t1,
                                 float* __restrict__ ws)
{
  int o = threadIdx.x;
  const float Mf = (float)MPTS;
  float mean = ws[OFF_S1SUM+o]/Mf;
  float var  = ws[OFF_S1SQ+o]/Mf - mean*mean;
  float sc = g1[o]/sqrtf(var+EPSF);
  ws[OFF_SC1+o]=sc; ws[OFF_SH1+o]=t1[o]-mean*sc;
}

// MFMA layer 2: C[512K x 128] = relu(bn1(Y1))[512K x 64] * W2[64 x 128] + b2.
// 16x16x32 bf16 MFMA. A-frag: m=lane&15 (point), k=(lane>>4)*8+j (contig 16B
// from point-major y1, BN1 affine+relu applied in-register). B staged in LDS
// in fragment order. D (m89-verified): col=lane&15, row=(lane>>4)*4+r.
__global__ __launch_bounds__(256) void l2_mfma_kernel(
    const float* __restrict__ w2g, const float* __restrict__ b2g,
    float* __restrict__ ws)
{
  __shared__ __align__(16) unsigned short sB[8192]; // [nt][kt][lane][j]
  __shared__ float s1c[64], s1h[64];
  __shared__ float red[256];
  const int tid = threadIdx.x;
  for (int idx=tid; idx<8192; idx+=256){
    int nt = idx>>10, kt = (idx>>9)&1, l = (idx>>3)&63, j = idx&7;
    int kch = kt*32 + ((l>>4)<<3) + j;
    int o   = (nt<<4) + (l&15);
    sB[idx] = (unsigned short)rne_bf16(w2g[o*64+kch]);
  }
  if (tid<64){ s1c[tid]=ws[OFF_SC1+tid]; s1h[tid]=ws[OFF_SH1+tid]; }
  red[tid]=0.f;
  __syncthreads();

  const int lane = tid & 63;
  const int w    = tid >> 6;
  const int col  = lane & 15;
  const int kg   = lane >> 4;    // 0..3

  float scv[2][8], shv[2][8];
  #pragma unroll
  for (int kt=0;kt<2;kt++)
    #pragma unroll
    for (int j=0;j<8;j++){
      scv[kt][j] = s1c[kt*32 + kg*8 + j];
      shv[kt][j] = s1h[kt*32 + kg*8 + j];
    }
  float b2v[8];
  #pragma unroll
  for (int nt=0;nt<8;nt++) b2v[nt] = b2g[nt*16 + col];

  const unsigned short* y1 = (const unsigned short*)(ws + OFF_Y1U);
  float* maxb = ws + OFF_MAXB;
  float* minb = ws + OFF_MINB;

  float sumacc[8], sqacc[8];
  #pragma unroll
  for (int nt=0;nt<8;nt++){ sumacc[nt]=0.f; sqacc[nt]=0.f; }

  const int gbase = (blockIdx.x*4 + w)*4;
  for (int it=0; it<4; ++it){
    const int g = gbase + it;
    const size_t p0 = (size_t)g*32;
    bf16x8 aA[2][2];
    #pragma unroll
    for (int mh=0; mh<2; ++mh){
      const unsigned short* arow = y1 + (p0 + mh*16 + col)*64 + kg*8;
      #pragma unroll
      for (int kt=0; kt<2; ++kt){
        uintx4 ua = *reinterpret_cast<const uintx4*>(arow + kt*32);
        float h0 = fmaxf(fmaf(scv[kt][0], __uint_as_float(ua[0]<<16),          shv[kt][0]), 0.f);
        float h1 = fmaxf(fmaf(scv[kt][1], __uint_as_float(ua[0]&0xFFFF0000u), shv[kt][1]), 0.f);
        float h2 = fmaxf(fmaf(scv[kt][2], __uint_as_float(ua[1]<<16),          shv[kt][2]), 0.f);
        float h3 = fmaxf(fmaf(scv[kt][3], __uint_as_float(ua[1]&0xFFFF0000u), shv[kt][3]), 0.f);
        float h4 = fmaxf(fmaf(scv[kt][4], __uint_as_float(ua[2]<<16),          shv[kt][4]), 0.f);
        float h5 = fmaxf(fmaf(scv[kt][5], __uint_as_float(ua[2]&0xFFFF0000u), shv[kt][5]), 0.f);
        float h6 = fmaxf(fmaf(scv[kt][6], __uint_as_float(ua[3]<<16),          shv[kt][6]), 0.f);
        float h7 = fmaxf(fmaf(scv[kt][7], __uint_as_float(ua[3]&0xFFFF0000u), shv[kt][7]), 0.f);
        uintx4 pk;
        pk[0] = rne_bf16(h0) | (rne_bf16(h1)<<16);
        pk[1] = rne_bf16(h2) | (rne_bf16(h3)<<16);
        pk[2] = rne_bf16(h4) | (rne_bf16(h5)<<16);
        pk[3] = rne_bf16(h6) | (rne_bf16(h7)<<16);
        aA[mh][kt] = __builtin_bit_cast(bf16x8, pk);
      }
    }
    f32x4 acc[2][8];
    #pragma unroll
    for (int mh=0;mh<2;mh++)
      #pragma unroll
      for (int nt=0;nt<8;nt++){
        f32x4 z = {b2v[nt], b2v[nt], b2v[nt], b2v[nt]};
        acc[mh][nt] = z;
      }
    #pragma unroll
    for (int nt=0;nt<8;nt++){
      #pragma unroll
      for (int kt=0;kt<2;kt++){
        uintx4 bu = *reinterpret_cast<const uintx4*>(&sB[((nt*2+kt)*64 + lane)*8]);
        bf16x8 bv = __builtin_bit_cast(bf16x8, bu);
        acc[0][nt] = __builtin_amdgcn_mfma_f32_16x16x32_bf16(aA[0][kt], bv, acc[0][nt], 0,0,0);
        acc[1][nt] = __builtin_amdgcn_mfma_f32_16x16x32_bf16(aA[1][kt], bv, acc[1][nt], 0,0,0);
      }
    }
    #pragma unroll
    for (int nt=0;nt<8;nt++){
      f32x4 a0 = acc[0][nt], a1 = acc[1][nt];
      float mx = fmaxf(fmaxf(fmaxf(a0[0],a0[1]),fmaxf(a0[2],a0[3])),
                       fmaxf(fmaxf(a1[0],a1[1]),fmaxf(a1[2],a1[3])));
      float mn = fminf(fminf(fminf(a0[0],a0[1]),fminf(a0[2],a0[3])),
                       fminf(fminf(a1[0],a1[1]),fminf(a1[2],a1[3])));
      mx = fmaxf(mx, __shfl_xor(mx,16,64)); mx = fmaxf(mx, __shfl_xor(mx,32,64));
      mn = fminf(mn, __shfl_xor(mn,16,64)); mn = fminf(mn, __shfl_xor(mn,32,64));
      float s = ((a0[0]+a0[1])+(a0[2]+a0[3])) + ((a1[0]+a1[1])+(a1[2]+a1[3]));
      sumacc[nt] += s;
      float qv = 0.f;
      qv = fmaf(a0[0],a0[0],qv); qv = fmaf(a0[1],a0[1],qv);
      qv = fmaf(a0[2],a0[2],qv); qv = fmaf(a0[3],a0[3],qv);
      qv = fmaf(a1[0],a1[0],qv); qv = fmaf(a1[1],a1[1],qv);
      qv = fmaf(a1[2],a1[2],qv); qv = fmaf(a1[3],a1[3],qv);
      sqacc[nt] += qv;
      if (lane < 16){
        maxb[(size_t)g*128 + nt*16 + lane] = mx;
        minb[(size_t)g*128 + nt*16 + lane] = mn;
      }
    }
  }
  #pragma unroll
  for (int nt=0;nt<8;nt++){
    float s = sumacc[nt]; s += __shfl_xor(s,16,64); s += __shfl_xor(s,32,64);
    float qv = sqacc[nt]; qv += __shfl_xor(qv,16,64); qv += __shfl_xor(qv,32,64);
    if (lane < 16){
      atomicAdd(&red[nt*16+lane], s);
      atomicAdd(&red[128+nt*16+lane], qv);
    }
  }
  __syncthreads();
  atomicAdd(&ws[OFF_S2SUM + tid], red[tid]);
}

__global__ __launch_bounds__(256) void final_out_kernel(
    const float* __restrict__ g2, const float* __restrict__ t2,
    const float* __restrict__ ws, float* __restrict__ out)
{
  const int g = blockIdx.x*256 + threadIdx.x; // B*S*128 threads
  const int o = g & 127;
  const float Mf = (float)MPTS;
  float mean = ws[OFF_S2SUM+o] / Mf;
  float var  = ws[OFF_S2SQ+o] / Mf - mean*mean;
  float sc = g2[o] / sqrtf(var + EPSF);
  float sh = t2[o] - mean*sc;
  float v = (sc > 0.f) ? ws[OFF_MAXB+g] : ws[OFF_MINB+g];
  out[BB*SS*3 + g] = fmaxf(fmaf(sc, v, sh), 0.f);
}

extern "C" void kernel_launch(void* const* d_in, const int* in_sizes, int n_in,
                              void* d_out, int out_size, void* d_ws, size_t ws_size,
                              hipStream_t stream)
{
  const float* xyz = (const float*)d_in[0];
  const float* pts = (const float*)d_in[1];
  const int*   fps = (const int*)d_in[2];
  const float* w0  = (const float*)d_in[3];
  const float* b0  = (const float*)d_in[4];
  const float* g0  = (const float*)d_in[5];
  const float* t0  = (const float*)d_in[6];
  const float* w1  = (const float*)d_in[7];
  const float* b1  = (const float*)d_in[8];
  const float* g1  = (const float*)d_in[9];
  const float* t1  = (const float*)d_in[10];
  const float* w2  = (const float*)d_in[11];
  const float* b2  = (const float*)d_in[12];
  const float* g2  = (const float*)d_in[13];
  const float* t2  = (const float*)d_in[14];
  float* out = (float*)d_out;
  float* ws  = (float*)d_ws;

  hipMemsetAsync((void*)(ws + OFF_ST), 0, 512*sizeof(float), stream);
  prep_kernel<<<320,256,0,stream>>>(xyz, fps, out, ws);
  knn_group_kernel<<<BB*SS,256,0,stream>>>(pts, ws);
  mom_reduce_kernel<<<27,256,0,stream>>>(ws);
  finalize0_kernel<<<1,64,0,stream>>>(w0,b0,g0,t0,ws);
  l1_kernel<<<MPTS/256,256,0,stream>>>(w0,b0,w1,b1,ws);
  stats1_kernel<<<256,256,0,stream>>>(ws);
  finalize1_kernel<<<1,64,0,stream>>>(g1,t1,ws);
  l2_mfma_kernel<<<1024,256,0,stream>>>(w2,b2,ws);
  final_out_kernel<<<(BB*SS*128)/256,256,0,stream>>>(g2,t2,ws,out);
}

// Round 9
// 419.543 us; speedup vs baseline: 46.6850x; 1.0619x over previous
//
#include <hip/hip_runtime.h>

#define BB 16
#define NN 4096
#define SS 1024
#define KK 32
#define MPTS (BB*SS*KK)      // 524288
#define EPSF 1e-5f
#define CANDCAP 512
#define NARROW 48

// workspace layout (float offsets)
#define OFF_QP    0                       // B*S*4
#define OFF_P4    (OFF_QP + BB*SS*4)      // B*N*4
#define OFF_ST    (OFF_P4 + BB*NN*4)      // 512 floats zeroed each call
#define OFF_MOM   (OFF_ST)                // 27
#define OFF_S1SUM (OFF_ST+32)             // 64
#define OFF_S1SQ  (OFF_ST+96)             // 64
#define OFF_S2SUM (OFF_ST+160)            // 128
#define OFF_S2SQ  (OFF_ST+288)            // 128
#define OFF_XG    (OFF_ST+1280)           // 6*MPTS channel-major
#define OFF_MAXB  (OFF_XG + 6*MPTS)       // B*S*128
#define OFF_MINB  (OFF_MAXB + BB*SS*128)  // B*S*128
#define OFF_Y1U   (OFF_MINB + BB*SS*128)  // bf16 (ushort) POINT-major [MPTS][64]
// knn's per-block moment partials [27][BB*SS] reuse the Y1U region (l1
// overwrites it only after mom_reduce has consumed the partials)
#define OFF_MOMP  (OFF_Y1U)

typedef __bf16 bf16x8 __attribute__((ext_vector_type(8)));
typedef float f32x4 __attribute__((ext_vector_type(4)));
typedef unsigned int uintx4 __attribute__((ext_vector_type(4)));

__device__ __forceinline__ unsigned rne_bf16(float f){
  unsigned u = __float_as_uint(f);
  return (u + 0x7FFFu + ((u>>16)&1u)) >> 16;   // RNE f32->bf16 (finite, non-NaN)
}

__global__ __launch_bounds__(256) void prep_kernel(
    const float* __restrict__ xyz, const int* __restrict__ fps,
    float* __restrict__ out, float* __restrict__ ws)
{
  const int g = blockIdx.x*256 + threadIdx.x;
  if (g < BB*NN){
    const float* p = xyz + (size_t)g*3;
    float x=p[0], y=p[1], z=p[2];
    float x2 = __fadd_rn(__fadd_rn(__fmul_rn(x,x),__fmul_rn(y,y)),__fmul_rn(z,z));
    *reinterpret_cast<float4*>(ws + OFF_P4 + (size_t)g*4) = make_float4(x,y,z,x2);
  } else {
    int j = g - BB*NN;
    if (j < BB*SS){
      int b = j >> 10;
      int idx = fps[j];
      const float* p = xyz + ((size_t)b*NN + idx)*3;
      float x=p[0], y=p[1], z=p[2];
      out[(size_t)j*3+0]=x; out[(size_t)j*3+1]=y; out[(size_t)j*3+2]=z;
      float q2 = __fadd_rn(__fadd_rn(__fmul_rn(x,x),__fmul_rn(y,y)),__fmul_rn(z,z));
      *reinterpret_cast<float4*>(ws + OFF_QP + (size_t)j*4) = make_float4(x,y,z,q2);
    }
  }
}

// one block per query: exact 32-NN. Keys in registers; histogram levels
// narrow until boundary-bin count <= NARROW (typically 2 passes); compact
// candidates as packed (key<<32|idx) u64; exact parallel rank-select.
__global__ __launch_bounds__(256) void knn_group_kernel(
    const float* __restrict__ pts, float* __restrict__ ws)
{
  __shared__ unsigned hist[256];
  __shared__ unsigned wsum[4];
  __shared__ unsigned long long cand[CANDCAP];
  __shared__ int sel[KK];
  __shared__ unsigned sh_b, sh_kk, sh_m;
  __shared__ int sh_nlt;
  __shared__ unsigned sh_mcnt;

  const int bid = blockIdx.x;
  const int b = bid >> 10;
  const int tid = threadIdx.x;
  const int lane = tid & 63;
  const int wv = tid >> 6;

  const float4 q = *reinterpret_cast<const float4*>(ws + OFF_QP + (size_t)bid*4);
  const float qx=q.x, qy=q.y, qz=q.z, q2=q.w;
  const float4* pb = reinterpret_cast<const float4*>(ws + OFF_P4) + (size_t)b*NN;

  unsigned k[16];            // static-indexed only (all loops unrolled)
  #pragma unroll
  for (int j=0;j<16;j++){
    int n = tid + j*256;
    float4 P = pb[n];
    float dot = __fadd_rn(__fadd_rn(__fmul_rn(qx,P.x),__fmul_rn(qy,P.y)),__fmul_rn(qz,P.z));
    float d = __fsub_rn(__fadd_rn(q2, P.w), __fmul_rn(2.0f,dot));
    unsigned u = __float_as_uint(d);
    k[j] = u ^ (unsigned)(((int)u>>31) | (int)0x80000000);
  }

  const unsigned long long mlt = (lane==0) ? 0ull : (~0ull >> (64-lane));
  unsigned maskhi = 0, prefix = 0;
  int kk = KK;
  int Ls = 3;
  unsigned bs = 0;
  for (int L=3; L>=0; --L){
    const int shift = L*8;
    hist[tid] = 0;
    __syncthreads();
    if (L==3){
      // all keys active: ballot-leader counting (bins concentrate)
      #pragma unroll
      for (int j=0;j<16;j++){
        unsigned bin = k[j]>>24;
        unsigned long long bm = ~0ull;
        #pragma unroll
        for (int bit=0;bit<8;bit++){
          unsigned long long bb = __ballot((int)((bin>>bit)&1u));
          bm &= ((bin>>bit)&1u) ? bb : ~bb;
        }
        if ((bm & mlt) == 0ull) atomicAdd(&hist[bin], (unsigned)__popcll(bm));
      }
    } else {
      // few active keys, spread bins: plain atomics are fine
      #pragma unroll
      for (int j=0;j<16;j++){
        if ((k[j] & maskhi) == prefix) atomicAdd(&hist[(k[j]>>shift)&0xFFu], 1u);
      }
    }
    __syncthreads();
    unsigned orig = hist[tid];
    unsigned v = orig;
    #pragma unroll
    for (int off=1; off<64; off<<=1){
      unsigned u = __shfl_up(v, (unsigned)off, 64);
      if (lane >= off) v += u;
    }
    if (lane==63) wsum[wv] = v;
    __syncthreads();
    unsigned add = 0;
    #pragma unroll
    for (int kq=0;kq<3;kq++) if (wv > kq) add += wsum[kq];
    unsigned cum = v + add;
    unsigned lower = cum - orig;
    if (cum >= (unsigned)kk && lower < (unsigned)kk){
      sh_b = (unsigned)tid; sh_kk = (unsigned)kk - lower; sh_m = orig;
    }
    __syncthreads();
    unsigned bnow = sh_b; kk = (int)sh_kk;
    unsigned m = sh_m;
    if (m <= NARROW || L == 0){ bs = bnow; Ls = L; break; }
    prefix |= bnow << shift;
    maskhi |= 0xFFu << shift;
  }
  const int shf = Ls*8;
  const unsigned M = maskhi | (0xFFu << shf);
  const unsigned T = prefix | (bs << shf);

  if (tid==0){ sh_nlt = 0; sh_mcnt = 0; }
  __syncthreads();
  #pragma unroll
  for (int j=0;j<16;j++){
    unsigned mk = k[j] & M;
    int n = tid + j*256;
    if (mk < T){ int p = atomicAdd(&sh_nlt,1); sel[p] = n; }
    else if (mk == T){
      unsigned p = atomicAdd(&sh_mcnt,1u);
      if (p < CANDCAP) cand[p] = ((unsigned long long)k[j]<<32) | (unsigned)n;
    }
  }
  __syncthreads();
  const int nlt = sh_nlt;                  // == KK - kk
  const unsigned m = (sh_mcnt < CANDCAP) ? sh_mcnt : CANDCAP;
  // exact rank among candidates: (key, idx) lexicographic == packed u64 order
  for (unsigned i=tid; i<m; i+=256){
    const unsigned long long ci = cand[i];
    unsigned r = 0;
    #pragma unroll 4
    for (unsigned jj=0; jj<m; ++jj) r += (cand[jj] < ci) ? 1u : 0u;
    if (r < (unsigned)kk) sel[nlt + (int)r] = (int)(ci & 0xFFFFFFFFu);
  }
  __syncthreads();

  if (tid < KK){
    int n = sel[tid];
    float4 P = pb[n];
    float v6[6];
    v6[0] = P.x-qx; v6[1] = P.y-qy; v6[2] = P.z-qz;
    const float* pt = pts + ((size_t)b*NN + n)*3;
    v6[3] = pt[0]; v6[4] = pt[1]; v6[5] = pt[2];
    size_t pidx = (size_t)bid*KK + tid;
    float* xg = ws + OFF_XG;
    #pragma unroll
    for (int c=0;c<6;c++) xg[(size_t)c*MPTS + pidx] = v6[c];
    float mm[27];
    int mi = 0;
    #pragma unroll
    for (int c=0;c<6;c++) mm[mi++] = v6[c];
    #pragma unroll
    for (int c=0;c<6;c++){
      #pragma unroll
      for (int c2=c;c2<6;c2++) mm[mi++] = v6[c]*v6[c2];
    }
    #pragma unroll
    for (int off=16; off>=1; off>>=1){
      #pragma unroll
      for (int qq=0;qq<27;qq++) mm[qq] += __shfl_xor(mm[qq], off, 64);
    }
    if (tid==0){
      float* momp = ws + OFF_MOMP;
      #pragma unroll
      for (int qq=0;qq<27;qq++) momp[(size_t)qq*(BB*SS) + bid] = mm[qq];
    }
  }
}

// sum the [27][16384] partials -> OFF_MOM
__global__ __launch_bounds__(256) void mom_reduce_kernel(float* __restrict__ ws)
{
  const int q = blockIdx.x;
  const float* src = ws + OFF_MOMP + (size_t)q*(BB*SS);
  float s = 0.f;
  for (int i=threadIdx.x; i<BB*SS; i+=256) s += src[i];
  #pragma unroll
  for (int off=32; off>=1; off>>=1) s += __shfl_xor(s,off,64);
  __shared__ float r[4];
  const int lane = threadIdx.x & 63, wv = threadIdx.x >> 6;
  if (lane==0) r[wv]=s;
  __syncthreads();
  if (threadIdx.x==0) ws[OFF_MOM+q] = r[0]+r[1]+r[2]+r[3];
}

// thread = point: finalize0 folded into staging (tid<64 computes sc0/sh0 from
// the 27 moments); recompute h0 per channel on the fly, accumulate y1 in two
// chunks of 32, store raw y1 as bf16 POINT-major [p][64].
__global__ __launch_bounds__(256) void l1_kernel(
    const float* __restrict__ w0g, const float* __restrict__ b0g,
    const float* __restrict__ g0, const float* __restrict__ t0,
    const float* __restrict__ w1g, const float* __restrict__ b1g,
    float* __restrict__ ws)
{
  __shared__ float sw0[64*8];    // w0[c][0..5] at c*8
  __shared__ float sw1T[4096];   // [c][o]
  __shared__ float sb0[64], ssc0[64], ssh0[64], sb1[64];
  const int tid = threadIdx.x;
  for (int i=tid;i<384;i+=256){ int o=i/6, c=i-o*6; sw0[o*8+c] = w0g[i]; }
  for (int i=tid;i<4096;i+=256){ int c=i>>6, o=i&63; sw1T[c*64+o] = w1g[o*64+c]; }
  if (tid<64){
    // finalize0: BN0 scale/shift from input moments
    const float* mom = ws + OFF_MOM;
    float w[6];
    #pragma unroll
    for (int c=0;c<6;c++) w[c] = w0g[tid*6+c];
    float bo = b0g[tid];
    float wS = 0.f;
    #pragma unroll
    for (int c=0;c<6;c++) wS += w[c]*mom[c];
    const float Mf = (float)MPTS;
    float mean = (wS + Mf*bo) / Mf;
    float qsum = 0.f;
    int mi = 6;
    #pragma unroll
    for (int c=0;c<6;c++){
      #pragma unroll
      for (int c2=c;c2<6;c2++){
        float f = (c==c2)?1.f:2.f;
        qsum += f * w[c]*w[c2]*mom[mi];
        mi++;
      }
    }
    float E2  = (qsum + 2.f*bo*wS + Mf*bo*bo) / Mf;
    float var = E2 - mean*mean;
    float sc  = g0[tid] / sqrtf(var + EPSF);
    ssc0[tid] = sc;
    ssh0[tid] = t0[tid] - mean*sc;
    sb0[tid] = bo; sb1[tid] = b1g[tid];
  }
  __syncthreads();

  const size_t p = (size_t)blockIdx.x*256 + tid;
  const float* xg = ws + OFF_XG;
  const float x0=xg[p],        x1=xg[MPTS+p],   x2=xg[2ul*MPTS+p];
  const float x3=xg[3ul*MPTS+p], x4=xg[4ul*MPTS+p], x5=xg[5ul*MPTS+p];
  unsigned short* y1 = (unsigned short*)(ws + OFF_Y1U);

  for (int ch=0; ch<2; ++ch){
    float a[32];
    #pragma unroll
    for (int j=0;j<32;j++) a[j] = sb1[ch*32+j];
    for (int c=0;c<64;c++){
      const float4 wa = *reinterpret_cast<const float4*>(&sw0[c*8]);
      const float2 wb = *reinterpret_cast<const float2*>(&sw0[c*8+4]);
      float y = sb0[c];
      y = fmaf(wa.x,x0,y); y = fmaf(wa.y,x1,y); y = fmaf(wa.z,x2,y);
      y = fmaf(wa.w,x3,y); y = fmaf(wb.x,x4,y); y = fmaf(wb.y,x5,y);
      const float h = fmaxf(fmaf(ssc0[c], y, ssh0[c]), 0.f);
      const float4* wr = reinterpret_cast<const float4*>(&sw1T[c*64 + ch*32]);
      #pragma unroll
      for (int qq=0;qq<8;qq++){
        float4 wvv = wr[qq];
        a[qq*4+0] = fmaf(wvv.x,h,a[qq*4+0]);
        a[qq*4+1] = fmaf(wvv.y,h,a[qq*4+1]);
        a[qq*4+2] = fmaf(wvv.z,h,a[qq*4+2]);
        a[qq*4+3] = fmaf(wvv.w,h,a[qq*4+3]);
      }
    }
    unsigned uu[16];
    #pragma unroll
    for (int j=0;j<16;j++)
      uu[j] = rne_bf16(a[2*j]) | (rne_bf16(a[2*j+1])<<16);
    uint4* dst = reinterpret_cast<uint4*>(y1 + p*64 + ch*32);
    #pragma unroll
    for (int qq=0;qq<4;qq++)
      dst[qq] = make_uint4(uu[qq*4+0],uu[qq*4+1],uu[qq*4+2],uu[qq*4+3]);
  }
}

// per-channel sum/sumsq of y1 (bf16, point-major)
__global__ __launch_bounds__(256) void stats1_kernel(float* __restrict__ ws)
{
  __shared__ float redS[64], redQ[64];
  const int tid = threadIdx.x;
  if (tid<64){ redS[tid]=0.f; redQ[tid]=0.f; }
  __syncthreads();
  const int lane = tid & 63;
  const int c0 = (lane & 15)*4;     // channels c0..c0+3
  const int prow = tid >> 4;        // 0..15
  const unsigned short* y1 = (const unsigned short*)(ws + OFF_Y1U);
  const int base = blockIdx.x * 2048;
  float sv0=0,sv1=0,sv2=0,sv3=0, sq0=0,sq1=0,sq2=0,sq3=0;
  for (int p = base + prow; p < base + 2048; p += 16){
    uint2 u = *reinterpret_cast<const uint2*>(y1 + (size_t)p*64 + c0);
    float v0 = __uint_as_float(u.x<<16);
    float v1 = __uint_as_float(u.x & 0xFFFF0000u);
    float v2 = __uint_as_float(u.y<<16);
    float v3 = __uint_as_float(u.y & 0xFFFF0000u);
    sv0+=v0; sv1+=v1; sv2+=v2; sv3+=v3;
    sq0=fmaf(v0,v0,sq0); sq1=fmaf(v1,v1,sq1); sq2=fmaf(v2,v2,sq2); sq3=fmaf(v3,v3,sq3);
  }
  sv0 += __shfl_xor(sv0,16,64); sv0 += __shfl_xor(sv0,32,64);
  sv1 += __shfl_xor(sv1,16,64); sv1 += __shfl_xor(sv1,32,64);
  sv2 += __shfl_xor(sv2,16,64); sv2 += __shfl_xor(sv2,32,64);
  sv3 += __shfl_xor(sv3,16,64); sv3 += __shfl_xor(sv3,32,64);
  sq0 += __shfl_xor(sq0,16,64); sq0 += __shfl_xor(sq0,32,64);
  sq1 += __shfl_xor(sq1,16,64); sq1 += __shfl_xor(sq1,32,64);
  sq2 += __shfl_xor(sq2,16,64); sq2 += __shfl_xor(sq2,32,64);
  sq3 += __shfl_xor(sq3,16,64); sq3 += __shfl_xor(sq3,32,64);
  if (lane < 16){
    atomicAdd(&redS[c0+0], sv0); atomicAdd(&redS[c0+1], sv1);
    atomicAdd(&redS[c0+2], sv2); atomicAdd(&redS[c0+3], sv3);
    atomicAdd(&redQ[c0+0], sq0); atomicAdd(&redQ[c0+1], sq1);
    atomicAdd(&redQ[c0+2], sq2); atomicAdd(&redQ[c0+3], sq3);
  }
  __syncthreads();
  if (tid < 64){
    atomicAdd(&ws[OFF_S1SUM+tid], redS[tid]);
    atomicAdd(&ws[OFF_S1SQ+tid],  redQ[tid]);
  }
}

// MFMA layer 2 with finalize1 folded into staging (tid<64 computes sc1/sh1).
// C[512K x 128] = relu(bn1(Y1))[512K x 64] * W2[64 x 128] + b2.
// A-frag: m=lane&15 (point), k=(lane>>4)*8+j; D: col=lane&15, row=(lane>>4)*4+r.
__global__ __launch_bounds__(256) void l2_mfma_kernel(
    const float* __restrict__ w2g, const float* __restrict__ b2g,
    const float* __restrict__ g1, const float* __restrict__ t1,
    float* __restrict__ ws)
{
  __shared__ __align__(16) unsigned short sB[8192]; // [nt][kt][lane][j]
  __shared__ float s1c[64], s1h[64];
  __shared__ float red[256];
  const int tid = threadIdx.x;
  for (int idx=tid; idx<8192; idx+=256){
    int nt = idx>>10, kt = (idx>>9)&1, l = (idx>>3)&63, j = idx&7;
    int kch = kt*32 + ((l>>4)<<3) + j;
    int o   = (nt<<4) + (l&15);
    sB[idx] = (unsigned short)rne_bf16(w2g[o*64+kch]);
  }
  if (tid<64){
    // finalize1: BN1 scale/shift from y1 stats
    const float Mf = (float)MPTS;
    float mean = ws[OFF_S1SUM+tid]/Mf;
    float var  = ws[OFF_S1SQ+tid]/Mf - mean*mean;
    float sc = g1[tid]/sqrtf(var+EPSF);
    s1c[tid]=sc; s1h[tid]=t1[tid]-mean*sc;
  }
  red[tid]=0.f;
  __syncthreads();

  const int lane = tid & 63;
  const int w    = tid >> 6;
  const int col  = lane & 15;
  const int kg   = lane >> 4;    // 0..3

  float scv[2][8], shv[2][8];
  #pragma unroll
  for (int kt=0;kt<2;kt++)
    #pragma unroll
    for (int j=0;j<8;j++){
      scv[kt][j] = s1c[kt*32 + kg*8 + j];
      shv[kt][j] = s1h[kt*32 + kg*8 + j];
    }
  float b2v[8];
  #pragma unroll
  for (int nt=0;nt<8;nt++) b2v[nt] = b2g[nt*16 + col];

  const unsigned short* y1 = (const unsigned short*)(ws + OFF_Y1U);
  float* maxb = ws + OFF_MAXB;
  float* minb = ws + OFF_MINB;

  float sumacc[8], sqacc[8];
  #pragma unroll
  for (int nt=0;nt<8;nt++){ sumacc[nt]=0.f; sqacc[nt]=0.f; }

  const int gbase = (blockIdx.x*4 + w)*4;
  for (int it=0; it<4; ++it){
    const int g = gbase + it;
    const size_t p0 = (size_t)g*32;
    bf16x8 aA[2][2];
    #pragma unroll
    for (int mh=0; mh<2; ++mh){
      const unsigned short* arow = y1 + (p0 + mh*16 + col)*64 + kg*8;
      #pragma unroll
      for (int kt=0; kt<2; ++kt){
        uintx4 ua = *reinterpret_cast<const uintx4*>(arow + kt*32);
        float h0 = fmaxf(fmaf(scv[kt][0], __uint_as_float(ua[0]<<16),          shv[kt][0]), 0.f);
        float h1 = fmaxf(fmaf(scv[kt][1], __uint_as_float(ua[0]&0xFFFF0000u), shv[kt][1]), 0.f);
        float h2 = fmaxf(fmaf(scv[kt][2], __uint_as_float(ua[1]<<16),          shv[kt][2]), 0.f);
        float h3 = fmaxf(fmaf(scv[kt][3], __uint_as_float(ua[1]&0xFFFF0000u), shv[kt][3]), 0.f);
        float h4 = fmaxf(fmaf(scv[kt][4], __uint_as_float(ua[2]<<16),          shv[kt][4]), 0.f);
        float h5 = fmaxf(fmaf(scv[kt][5], __uint_as_float(ua[2]&0xFFFF0000u), shv[kt][5]), 0.f);
        float h6 = fmaxf(fmaf(scv[kt][6], __uint_as_float(ua[3]<<16),          shv[kt][6]), 0.f);
        float h7 = fmaxf(fmaf(scv[kt][7], __uint_as_float(ua[3]&0xFFFF0000u), shv[kt][7]), 0.f);
        uintx4 pk;
        pk[0] = rne_bf16(h0) | (rne_bf16(h1)<<16);
        pk[1] = rne_bf16(h2) | (rne_bf16(h3)<<16);
        pk[2] = rne_bf16(h4) | (rne_bf16(h5)<<16);
        pk[3] = rne_bf16(h6) | (rne_bf16(h7)<<16);
        aA[mh][kt] = __builtin_bit_cast(bf16x8, pk);
      }
    }
    f32x4 acc[2][8];
    #pragma unroll
    for (int mh=0;mh<2;mh++)
      #pragma unroll
      for (int nt=0;nt<8;nt++){
        f32x4 z = {b2v[nt], b2v[nt], b2v[nt], b2v[nt]};
        acc[mh][nt] = z;
      }
    #pragma unroll
    for (int nt=0;nt<8;nt++){
      #pragma unroll
      for (int kt=0;kt<2;kt++){
        uintx4 bu = *reinterpret_cast<const uintx4*>(&sB[((nt*2+kt)*64 + lane)*8]);
        bf16x8 bv = __builtin_bit_cast(bf16x8, bu);
        acc[0][nt] = __builtin_amdgcn_mfma_f32_16x16x32_bf16(aA[0][kt], bv, acc[0][nt], 0,0,0);
        acc[1][nt] = __builtin_amdgcn_mfma_f32_16x16x32_bf16(aA[1][kt], bv, acc[1][nt], 0,0,0);
      }
    }
    #pragma unroll
    for (int nt=0;nt<8;nt++){
      f32x4 a0 = acc[0][nt], a1 = acc[1][nt];
      float mx = fmaxf(fmaxf(fmaxf(a0[0],a0[1]),fmaxf(a0[2],a0[3])),
                       fmaxf(fmaxf(a1[0],a1[1]),fmaxf(a1[2],a1[3])));
      float mn = fminf(fminf(fminf(a0[0],a0[1]),fminf(a0[2],a0[3])),
                       fminf(fminf(a1[0],a1[1]),fminf(a1[2],a1[3])));
      mx = fmaxf(mx, __shfl_xor(mx,16,64)); mx = fmaxf(mx, __shfl_xor(mx,32,64));
      mn = fminf(mn, __shfl_xor(mn,16,64)); mn = fminf(mn, __shfl_xor(mn,32,64));
      float s = ((a0[0]+a0[1])+(a0[2]+a0[3])) + ((a1[0]+a1[1])+(a1[2]+a1[3]));
      sumacc[nt] += s;
      float qv = 0.f;
      qv = fmaf(a0[0],a0[0],qv); qv = fmaf(a0[1],a0[1],qv);
      qv = fmaf(a0[2],a0[2],qv); qv = fmaf(a0[3],a0[3],qv);
      qv = fmaf(a1[0],a1[0],qv); qv = fmaf(a1[1],a1[1],qv);
      qv = fmaf(a1[2],a1[2],qv); qv = fmaf(a1[3],a1[3],qv);
      sqacc[nt] += qv;
      if (lane < 16){
        maxb[(size_t)g*128 + nt*16 + lane] = mx;
        minb[(size_t)g*128 + nt*16 + lane] = mn;
      }
    }
  }
  #pragma unroll
  for (int nt=0;nt<8;nt++){
    float s = sumacc[nt]; s += __shfl_xor(s,16,64); s += __shfl_xor(s,32,64);
    float qv = sqacc[nt]; qv += __shfl_xor(qv,16,64); qv += __shfl_xor(qv,32,64);
    if (lane < 16){
      atomicAdd(&red[nt*16+lane], s);
      atomicAdd(&red[128+nt*16+lane], qv);
    }
  }
  __syncthreads();
  atomicAdd(&ws[OFF_S2SUM + tid], red[tid]);
}

__global__ __launch_bounds__(256) void final_out_kernel(
    const float* __restrict__ g2, const float* __restrict__ t2,
    const float* __restrict__ ws, float* __restrict__ out)
{
  const int g = blockIdx.x*256 + threadIdx.x; // B*S*128 threads
  const int o = g & 127;
  const float Mf = (float)MPTS;
  float mean = ws[OFF_S2SUM+o] / Mf;
  float var  = ws[OFF_S2SQ+o] / Mf - mean*mean;
  float sc = g2[o] / sqrtf(var + EPSF);
  float sh = t2[o] - mean*sc;
  float v = (sc > 0.f) ? ws[OFF_MAXB+g] : ws[OFF_MINB+g];
  out[BB*SS*3 + g] = fmaxf(fmaf(sc, v, sh), 0.f);
}

extern "C" void kernel_launch(void* const* d_in, const int* in_sizes, int n_in,
                              void* d_out, int out_size, void* d_ws, size_t ws_size,
                              hipStream_t stream)
{
  const float* xyz = (const float*)d_in[0];
  const float* pts = (const float*)d_in[1];
  const int*   fps = (const int*)d_in[2];
  const float* w0  = (const float*)d_in[3];
  const float* b0  = (const float*)d_in[4];
  const float* g0  = (const float*)d_in[5];
  const float* t0  = (const float*)d_in[6];
  const float* w1  = (const float*)d_in[7];
  const float* b1  = (const float*)d_in[8];
  const float* g1  = (const float*)d_in[9];
  const float* t1  = (const float*)d_in[10];
  const float* w2  = (const float*)d_in[11];
  const float* b2  = (const float*)d_in[12];
  const float* g2  = (const float*)d_in[13];
  const float* t2  = (const float*)d_in[14];
  float* out = (float*)d_out;
  float* ws  = (float*)d_ws;

  hipMemsetAsync((void*)(ws + OFF_ST), 0, 512*sizeof(float), stream);
  prep_kernel<<<320,256,0,stream>>>(xyz, fps, out, ws);
  knn_group_kernel<<<BB*SS,256,0,stream>>>(pts, ws);
  mom_reduce_kernel<<<27,256,0,stream>>>(ws);
  l1_kernel<<<MPTS/256,256,0,stream>>>(w0,b0,g0,t0,w1,b1,ws);
  stats1_kernel<<<256,256,0,stream>>>(ws);
  l2_mfma_kernel<<<1024,256,0,stream>>>(w2,b2,g1,t1,ws);
  final_out_kernel<<<(BB*SS*128)/256,256,0,stream>>>(g2,t2,ws,out);
}